// Round 5
// baseline (1621.438 us; speedup 1.0000x reference)
//
#include <hip/hip_runtime.h>
#include <math.h>

#define LN_EPS 1e-5f
#define EPS_ATTN 1e-8f
#define SCALE 0.125f  // D^-0.5, D=64
#define CHUNKS 32

// ---------------------------------------------------------------------------
__device__ __forceinline__ float wave_reduce_add64(float v) {
#pragma unroll
  for (int m = 1; m <= 32; m <<= 1) v += __shfl_xor(v, m, 64);
  return v;
}

// 16-lane allreduce sum on the VALU pipe via DPP (no LDS-pipe traffic).
__device__ __forceinline__ float red16(float v) {
  v += __int_as_float(__builtin_amdgcn_update_dpp(0, __float_as_int(v), 0xB1, 0xF, 0xF, true));
  v += __int_as_float(__builtin_amdgcn_update_dpp(0, __float_as_int(v), 0x4E, 0xF, 0xF, true));
  v += __int_as_float(__builtin_amdgcn_update_dpp(0, __float_as_int(v), 0x124, 0xF, 0xF, true));
  v += __int_as_float(__builtin_amdgcn_update_dpp(0, __float_as_int(v), 0x128, 0xF, 0xF, true));
  return v;
}

// device-scope coherent load (bypasses potentially-stale L1/L2 copies)
__device__ __forceinline__ float cload(const float* p) {
  return __hip_atomic_load(p, __ATOMIC_RELAXED, __HIP_MEMORY_SCOPE_AGENT);
}

// ---------------------------------------------------------------------------
// One-time prep: M = scale*wq@wk^T, cvec = scale*bq@wk^T, uvec = scale*wq@bk,
// s0 = scale*bq.bk
__global__ __launch_bounds__(256) void k_prep(
    const float* __restrict__ wq, const float* __restrict__ wk,
    const float* __restrict__ bq, const float* __restrict__ bk,
    float* __restrict__ M, float* __restrict__ cvec,
    float* __restrict__ uvec, float* __restrict__ s0v)
{
  __shared__ float wqs[64 * 64];
  __shared__ float wks[64 * 65];
  int tid = threadIdx.x;
  for (int i = tid; i < 4096; i += 256) wqs[i] = wq[i];
  for (int i = tid; i < 4096; i += 256) wks[(i >> 6) * 65 + (i & 63)] = wk[i];
  __syncthreads();

  int idx = blockIdx.x * 256 + tid;
  int t = idx >> 6, d = idx & 63;
  float a = 0.0f;
#pragma unroll 8
  for (int j = 0; j < 64; ++j) a += wqs[t * 64 + j] * wks[d * 65 + j];
  M[idx] = a * SCALE;

  if (blockIdx.x == 0) {
    if (tid < 64) {
      float cc = 0.0f;
#pragma unroll 8
      for (int j = 0; j < 64; ++j) cc += bq[j] * wks[tid * 65 + j];
      cvec[tid] = cc * SCALE;
    } else if (tid < 128) {
      int t2 = tid - 64;
      float uu = 0.0f;
#pragma unroll 8
      for (int j = 0; j < 64; ++j) uu += wqs[t2 * 64 + j] * bk[j];
      uvec[t2] = uu * SCALE;
    } else if (tid == 128) {
      float ss = 0.0f;
      for (int j = 0; j < 64; ++j) ss += bq[j] * bk[j];
      s0v[0] = ss * SCALE;
    }
  }
}

// ---------------------------------------------------------------------------
// 256-thread slot->qk (sl replicated across the 4 waves, lane=d)
__device__ void slot_qk_256(int bi, float sl, int w, int lane,
    const float* __restrict__ M, const float* __restrict__ cvec,
    const float* __restrict__ uvec, const float* __restrict__ s0v,
    const float* __restrict__ g_sl, const float* __restrict__ beta_sl,
    float* __restrict__ qk, float* __restrict__ qb,
    float (*red)[64], float* vals)
{
  float s  = wave_reduce_add64(sl);
  float s2 = wave_reduce_add64(sl * sl);
  float mean = s * (1.0f / 64.0f);
  float var  = s2 * (1.0f / 64.0f) - mean * mean;
  float rstd = rsqrtf(var + LN_EPS);
  float ln = (sl - mean) * rstd * g_sl[lane] + beta_sl[lane];

  __syncthreads();
  if (w == 0) vals[lane] = ln;
  __syncthreads();

  float p = 0.0f;
#pragma unroll
  for (int j = 0; j < 16; ++j) {
    int t = w * 16 + j;
    p += vals[t] * M[t * 64 + lane];
  }
  red[w][lane] = p;
  if (w == 0) {
    float pb = wave_reduce_add64(ln * uvec[lane]);
    if (lane == 0) qb[bi] = s0v[0] + pb;
  }
  __syncthreads();
  if (w == 0)
    qk[bi * 64 + lane] = cvec[lane] + red[0][lane] + red[1][lane] + red[2][lane] + red[3][lane];
}

// ---------------------------------------------------------------------------
// Init: slots = mu + exp(log_sigma)*noise; zero accumulators + counters.
__global__ __launch_bounds__(256) void k_init(
    const float* __restrict__ noise, const float* __restrict__ mu,
    const float* __restrict__ lsig,
    const float* __restrict__ M, const float* __restrict__ cvec,
    const float* __restrict__ uvec, const float* __restrict__ s0v,
    const float* __restrict__ g_sl, const float* __restrict__ beta_sl,
    float* __restrict__ S_buf, float* __restrict__ qk, float* __restrict__ qb,
    float* __restrict__ acc, float* __restrict__ asum, int* __restrict__ cnt)
{
  __shared__ float vals[64];
  __shared__ float red[4][64];
  int bi = blockIdx.x;
  int tid = threadIdx.x, w = tid >> 6, lane = tid & 63;
  float sl = mu[lane] + __expf(lsig[lane]) * noise[bi * 64 + lane];
  if (w == 0) {
    S_buf[bi * 64 + lane] = sl;
    acc[bi * 64 + lane] = 0.0f;
    if (lane == 0) asum[bi] = 0.0f;
  }
  if (tid == 0 && bi < 64) cnt[bi] = 0;
  slot_qk_256(bi, sl, w, lane, M, cvec, uvec, s0v, g_sl, beta_sl, qk, qb, red, vals);
}

// ---------------------------------------------------------------------------
// Per-slot update (256 threads, lane=d), called by the last block of a batch.
// Reads acc/asum with device-coherent loads.
__device__ void slot_update(int bi, int tid, int w, int lane, int do_next,
    const float* __restrict__ S_in, float* __restrict__ S_out,
    float* __restrict__ acc, float* __restrict__ asum,
    const float* __restrict__ wv, const float* __restrict__ bv,
    const float* __restrict__ w_ih, const float* __restrict__ b_ih,
    const float* __restrict__ w_hh, const float* __restrict__ b_hh,
    const float* __restrict__ w1, const float* __restrict__ b1,
    const float* __restrict__ w2, const float* __restrict__ b2,
    const float* __restrict__ g_ff, const float* __restrict__ beta_ff,
    const float* __restrict__ M, const float* __restrict__ cvec,
    const float* __restrict__ uvec, const float* __restrict__ s0v,
    const float* __restrict__ g_sl, const float* __restrict__ beta_sl,
    float* __restrict__ qk, float* __restrict__ qb,
    float* vals, float (*redm)[4][64])
{
  float* redf = &redm[0][0][0];
  if (tid < 64) {
    float inv = 1.0f / cload(&asum[bi]);
    vals[tid] = cload(&acc[bi * 64 + tid]) * inv;
    if (do_next) {
      acc[bi * 64 + tid] = 0.0f;
      if (tid == 0) asum[bi] = 0.0f;
    }
  }
  float sp = S_in[bi * 64 + lane];
  __syncthreads();

  float pu = 0.0f;
#pragma unroll
  for (int j = 0; j < 16; ++j) {
    int e = w * 16 + j;
    pu += vals[e] * wv[e * 64 + lane];
  }
  redm[0][w][lane] = pu;
  __syncthreads();
  float upd = bv[lane] + redm[0][0][lane] + redm[0][1][lane] + redm[0][2][lane] + redm[0][3][lane];
  __syncthreads();
  if (w == 0) { vals[lane] = upd; vals[64 + lane] = sp; }
  __syncthreads();

  float pr = 0, pz = 0, pn = 0, qr = 0, qz = 0, qn = 0;
#pragma unroll 4
  for (int j = 0; j < 16; ++j) {
    int e = w * 16 + j;
    float uu = vals[e], hh = vals[64 + e];
    const float* wi = w_ih + e * 192;
    const float* wh = w_hh + e * 192;
    pr += uu * wi[lane]; pz += uu * wi[64 + lane]; pn += uu * wi[128 + lane];
    qr += hh * wh[lane]; qz += hh * wh[64 + lane]; qn += hh * wh[128 + lane];
  }
  redm[0][w][lane] = pr; redm[1][w][lane] = pz; redm[2][w][lane] = pn;
  redm[3][w][lane] = qr; redm[4][w][lane] = qz; redm[5][w][lane] = qn;
  __syncthreads();
  float gxr = b_ih[lane], gxz = b_ih[64 + lane], gxn = b_ih[128 + lane];
  float ghr = b_hh[lane], ghz = b_hh[64 + lane], ghn = b_hh[128 + lane];
#pragma unroll
  for (int k = 0; k < 4; ++k) {
    gxr += redm[0][k][lane]; gxz += redm[1][k][lane]; gxn += redm[2][k][lane];
    ghr += redm[3][k][lane]; ghz += redm[4][k][lane]; ghn += redm[5][k][lane];
  }
  float r  = 1.0f / (1.0f + __expf(-(gxr + ghr)));
  float z  = 1.0f / (1.0f + __expf(-(gxz + ghz)));
  float nw = tanhf(gxn + r * ghn);
  float sn = (1.0f - z) * nw + z * sp;

  float s  = wave_reduce_add64(sn);
  float s2 = wave_reduce_add64(sn * sn);
  float mean = s * (1.0f / 64.0f);
  float var  = s2 * (1.0f / 64.0f) - mean * mean;
  float rstd = rsqrtf(var + LN_EPS);
  float ff = (sn - mean) * rstd * g_ff[lane] + beta_ff[lane];
  __syncthreads();
  if (w == 0) vals[lane] = ff;
  __syncthreads();
  {
    int o = tid & 127, half = tid >> 7;
    float ph = 0.0f;
#pragma unroll 8
    for (int j = 0; j < 32; ++j) {
      int e = half * 32 + j;
      ph += vals[e] * w1[e * 128 + o];
    }
    redf[half * 128 + o] = ph;
  }
  __syncthreads();
  if (tid < 128)
    vals[tid] = fmaxf(b1[tid] + redf[tid] + redf[128 + tid], 0.0f);
  __syncthreads();

  float po = 0.0f;
#pragma unroll 8
  for (int j = 0; j < 32; ++j) {
    int t = w * 32 + j;
    po += vals[t] * w2[t * 64 + lane];
  }
  __syncthreads();
  redm[0][w][lane] = po;
  __syncthreads();
  float o = sn + b2[lane] + redm[0][0][lane] + redm[0][1][lane] + redm[0][2][lane] + redm[0][3][lane];
  if (w == 0) S_out[bi * 64 + lane] = o;

  if (do_next)
    slot_qk_256(bi, o, w, lane, M, cvec, uvec, s0v, g_sl, beta_sl, qk, qb,
                (float(*)[64])redf, vals);
  __syncthreads();  // protect vals/redm before next slot reuses them
}

// ---------------------------------------------------------------------------
// Fused main pass + last-block slot update. grid = (CHUNKS, 64), block = 256.
__global__ __launch_bounds__(256, 8) void k_fused(
    const float* __restrict__ inputs,
    const float* __restrict__ g_in, const float* __restrict__ beta_in,
    float* __restrict__ qk, float* __restrict__ qb,
    float* __restrict__ acc, float* __restrict__ asum,
    const float* __restrict__ S_in, float* __restrict__ S_out,
    const float* __restrict__ wv, const float* __restrict__ bv,
    const float* __restrict__ w_ih, const float* __restrict__ b_ih,
    const float* __restrict__ w_hh, const float* __restrict__ b_hh,
    const float* __restrict__ w1, const float* __restrict__ b1,
    const float* __restrict__ w2, const float* __restrict__ b2,
    const float* __restrict__ g_ff, const float* __restrict__ beta_ff,
    const float* __restrict__ M, const float* __restrict__ cvec,
    const float* __restrict__ uvec, const float* __restrict__ s0v,
    const float* __restrict__ g_sl, const float* __restrict__ beta_sl,
    int* __restrict__ cnt, int do_next)
{
  __shared__ float lds_acc[4][512];
  __shared__ float lds_as[4][8];
  __shared__ float vals[128];
  __shared__ float redm[6][4][64];
  __shared__ int is_last;
  const int b = blockIdx.y;
  const int chunk = blockIdx.x;
  const int tid = threadIdx.x;
  const int lane = tid & 63;
  const int wave = tid >> 6;
  const int p = lane & 15;

  float4 g4  = ((const float4*)g_in)[p];
  float4 be4 = ((const float4*)beta_in)[p];
  float4 qkv[8];
  float qbv[8];
  const float4* qk4 = (const float4*)(qk + b * 512);
#pragma unroll
  for (int i = 0; i < 8; ++i) {
    qkv[i] = qk4[i * 16 + p];
    qbv[i] = qb[b * 8 + i];
  }

  float4 accl[8];
  float asl[8];
#pragma unroll
  for (int i = 0; i < 8; ++i) { accl[i] = make_float4(0.f, 0.f, 0.f, 0.f); asl[i] = 0.f; }

  const float4* in4 = (const float4*)(inputs + (size_t)b * 4096 * 64);
  const int rb0 = chunk * 128 + wave * 4;

  float4 xv = in4[rb0 * 16 + lane];
  for (int it = 0; it < 8; ++it) {
    float4 nxt;
    if (it < 7) nxt = in4[(rb0 + (it + 1) * 16) * 16 + lane];  // prefetch

    float s  = red16(xv.x + xv.y + xv.z + xv.w);
    float s2 = red16(xv.x * xv.x + xv.y * xv.y + xv.z * xv.z + xv.w * xv.w);
    float mean = s * 0.015625f;
    float var  = s2 * 0.015625f - mean * mean;
    float rstd = rsqrtf(var + LN_EPS);
    float4 xln;
    xln.x = (xv.x - mean) * rstd * g4.x + be4.x;
    xln.y = (xv.y - mean) * rstd * g4.y + be4.y;
    xln.z = (xv.z - mean) * rstd * g4.z + be4.z;
    xln.w = (xv.w - mean) * rstd * g4.w + be4.w;

    float dots[8];
#pragma unroll
    for (int i = 0; i < 8; ++i) {
      float d = xln.x * qkv[i].x + xln.y * qkv[i].y + xln.z * qkv[i].z + xln.w * qkv[i].w;
      dots[i] = red16(d) + qbv[i];
    }

    float mx = dots[0];
#pragma unroll
    for (int i = 1; i < 8; ++i) mx = fmaxf(mx, dots[i]);
    float pv[8];
    float ps = 0.0f;
#pragma unroll
    for (int i = 0; i < 8; ++i) { pv[i] = __expf(dots[i] - mx); ps += pv[i]; }
    float inv = __builtin_amdgcn_rcpf(ps);
#pragma unroll
    for (int i = 0; i < 8; ++i) {
      float pp = pv[i] * inv + EPS_ATTN;
      asl[i] += pp;
      accl[i].x += pp * xln.x;
      accl[i].y += pp * xln.y;
      accl[i].z += pp * xln.z;
      accl[i].w += pp * xln.w;
    }
    xv = nxt;
  }

#pragma unroll
  for (int i = 0; i < 8; ++i) {
#pragma unroll
    for (int m = 16; m <= 32; m <<= 1) {
      accl[i].x += __shfl_xor(accl[i].x, m, 64);
      accl[i].y += __shfl_xor(accl[i].y, m, 64);
      accl[i].z += __shfl_xor(accl[i].z, m, 64);
      accl[i].w += __shfl_xor(accl[i].w, m, 64);
      asl[i]    += __shfl_xor(asl[i], m, 64);
    }
  }

  if (lane < 16) {
    float4* dst = (float4*)lds_acc[wave];
#pragma unroll
    for (int i = 0; i < 8; ++i) dst[i * 16 + p] = accl[i];
  }
  if (lane == 0) {
#pragma unroll
    for (int i = 0; i < 8; ++i) lds_as[wave][i] = asl[i];
  }
  __syncthreads();

  for (int f = tid; f < 512; f += 256) {
    float ssum = lds_acc[0][f] + lds_acc[1][f] + lds_acc[2][f] + lds_acc[3][f];
    atomicAdd(&acc[b * 512 + f], ssum);
  }
  if (tid < 8) {
    float ssum = lds_as[0][tid] + lds_as[1][tid] + lds_as[2][tid] + lds_as[3][tid];
    atomicAdd(&asum[b * 8 + tid], ssum);
  }

  // ---- completion detection: last block of this batch does the update ----
  __syncthreads();                 // drains each wave's outstanding atomics
  if (tid == 0) {
    __threadfence();               // release our acc/asum atomics
    int old = atomicAdd(&cnt[b], 1);
    is_last = (old == CHUNKS - 1);
    if (is_last) cnt[b] = 0;       // reset for next dispatch
  }
  __syncthreads();
  if (!is_last) return;
  __threadfence();                 // acquire side

  for (int i = 0; i < 8; ++i) {
    slot_update(b * 8 + i, tid, wave, lane, do_next,
                S_in, S_out, acc, asum, wv, bv, w_ih, b_ih, w_hh, b_hh,
                w1, b1, w2, b2, g_ff, beta_ff, M, cvec, uvec, s0v,
                g_sl, beta_sl, qk, qb, vals, redm);
  }
}

// ---------------------------------------------------------------------------
extern "C" void kernel_launch(void* const* d_in, const int* in_sizes, int n_in,
                              void* d_out, int out_size, void* d_ws, size_t ws_size,
                              hipStream_t stream) {
  const float* inputs  = (const float*)d_in[0];
  const float* noise   = (const float*)d_in[1];
  const float* mu      = (const float*)d_in[2];
  const float* lsig    = (const float*)d_in[3];
  const float* wq      = (const float*)d_in[4];
  const float* bq      = (const float*)d_in[5];
  const float* wk      = (const float*)d_in[6];
  const float* bk      = (const float*)d_in[7];
  const float* wv      = (const float*)d_in[8];
  const float* bv      = (const float*)d_in[9];
  const float* w_ih    = (const float*)d_in[10];
  const float* b_ih    = (const float*)d_in[11];
  const float* w_hh    = (const float*)d_in[12];
  const float* b_hh    = (const float*)d_in[13];
  const float* w1      = (const float*)d_in[14];
  const float* b1      = (const float*)d_in[15];
  const float* w2      = (const float*)d_in[16];
  const float* b2      = (const float*)d_in[17];
  const float* g_in    = (const float*)d_in[18];
  const float* beta_in = (const float*)d_in[19];
  const float* g_sl    = (const float*)d_in[20];
  const float* beta_sl = (const float*)d_in[21];
  const float* g_ff    = (const float*)d_in[22];
  const float* beta_ff = (const float*)d_in[23];

  float* S_buf = (float*)d_ws;        // [64*8*64]
  float* qk    = S_buf + 32768;       // [64*8*64]
  float* qb    = qk + 32768;          // [64*8]
  float* acc   = qb + 512;            // [64*8*64]
  float* asum  = acc + 32768;         // [64*8]
  float* M     = asum + 512;          // [64*64]
  float* cvec  = M + 4096;            // [64]
  float* uvec  = cvec + 64;           // [64]
  float* s0v   = uvec + 64;           // [1]
  int*   cnt   = (int*)(s0v + 1);     // [64]
  float* out   = (float*)d_out;

  k_prep<<<16, 256, 0, stream>>>(wq, wk, bq, bk, M, cvec, uvec, s0v);
  k_init<<<512, 256, 0, stream>>>(noise, mu, lsig, M, cvec, uvec, s0v,
                                  g_sl, beta_sl, S_buf, qk, qb, acc, asum, cnt);

  for (int t = 0; t < 3; ++t) {
    float* dst = (t == 2) ? out : S_buf;
    k_fused<<<dim3(CHUNKS, 64), 256, 0, stream>>>(
        inputs, g_in, beta_in, qk, qb, acc, asum, S_buf, dst,
        wv, bv, w_ih, b_ih, w_hh, b_hh, w1, b1, w2, b2,
        g_ff, beta_ff, M, cvec, uvec, s0v, g_sl, beta_sl,
        cnt, (t == 2) ? 0 : 1);
  }
}

// Round 6
// 731.278 us; speedup vs baseline: 2.2173x; 2.2173x over previous
//
#include <hip/hip_runtime.h>
#include <math.h>

#define LN_EPS 1e-5f
#define EPS_ATTN 1e-8f
#define SCALE 0.125f  // D^-0.5, D=64
#define CHUNKS 32

// ---------------------------------------------------------------------------
__device__ __forceinline__ float wave_reduce_add64(float v) {
#pragma unroll
  for (int m = 1; m <= 32; m <<= 1) v += __shfl_xor(v, m, 64);
  return v;
}

// 16-lane allreduce sum on the VALU pipe via DPP (no LDS-pipe traffic).
__device__ __forceinline__ float red16(float v) {
  v += __int_as_float(__builtin_amdgcn_update_dpp(0, __float_as_int(v), 0xB1, 0xF, 0xF, true));
  v += __int_as_float(__builtin_amdgcn_update_dpp(0, __float_as_int(v), 0x4E, 0xF, 0xF, true));
  v += __int_as_float(__builtin_amdgcn_update_dpp(0, __float_as_int(v), 0x124, 0xF, 0xF, true));
  v += __int_as_float(__builtin_amdgcn_update_dpp(0, __float_as_int(v), 0x128, 0xF, 0xF, true));
  return v;
}

// device-scope coherent load (bypasses potentially-stale L1/L2 copies)
__device__ __forceinline__ float cload(const float* p) {
  return __hip_atomic_load(p, __ATOMIC_RELAXED, __HIP_MEMORY_SCOPE_AGENT);
}

// ---------------------------------------------------------------------------
// One-time prep: M = scale*wq@wk^T, cvec = scale*bq@wk^T, uvec = scale*wq@bk,
// s0 = scale*bq.bk
__global__ __launch_bounds__(256) void k_prep(
    const float* __restrict__ wq, const float* __restrict__ wk,
    const float* __restrict__ bq, const float* __restrict__ bk,
    float* __restrict__ M, float* __restrict__ cvec,
    float* __restrict__ uvec, float* __restrict__ s0v)
{
  __shared__ float wqs[64 * 64];
  __shared__ float wks[64 * 65];
  int tid = threadIdx.x;
  for (int i = tid; i < 4096; i += 256) wqs[i] = wq[i];
  for (int i = tid; i < 4096; i += 256) wks[(i >> 6) * 65 + (i & 63)] = wk[i];
  __syncthreads();

  int idx = blockIdx.x * 256 + tid;
  int t = idx >> 6, d = idx & 63;
  float a = 0.0f;
#pragma unroll 8
  for (int j = 0; j < 64; ++j) a += wqs[t * 64 + j] * wks[d * 65 + j];
  M[idx] = a * SCALE;

  if (blockIdx.x == 0) {
    if (tid < 64) {
      float cc = 0.0f;
#pragma unroll 8
      for (int j = 0; j < 64; ++j) cc += bq[j] * wks[tid * 65 + j];
      cvec[tid] = cc * SCALE;
    } else if (tid < 128) {
      int t2 = tid - 64;
      float uu = 0.0f;
#pragma unroll 8
      for (int j = 0; j < 64; ++j) uu += wqs[t2 * 64 + j] * bk[j];
      uvec[t2] = uu * SCALE;
    } else if (tid == 128) {
      float ss = 0.0f;
      for (int j = 0; j < 64; ++j) ss += bq[j] * bk[j];
      s0v[0] = ss * SCALE;
    }
  }
}

// ---------------------------------------------------------------------------
// 256-thread slot->qk (sl replicated across the 4 waves, lane=d)
__device__ void slot_qk_256(int bi, float sl, int w, int lane,
    const float* __restrict__ M, const float* __restrict__ cvec,
    const float* __restrict__ uvec, const float* __restrict__ s0v,
    const float* __restrict__ g_sl, const float* __restrict__ beta_sl,
    float* __restrict__ qk, float* __restrict__ qb,
    float (*red)[64], float* vals)
{
  float s  = wave_reduce_add64(sl);
  float s2 = wave_reduce_add64(sl * sl);
  float mean = s * (1.0f / 64.0f);
  float var  = s2 * (1.0f / 64.0f) - mean * mean;
  float rstd = rsqrtf(var + LN_EPS);
  float ln = (sl - mean) * rstd * g_sl[lane] + beta_sl[lane];

  __syncthreads();
  if (w == 0) vals[lane] = ln;
  __syncthreads();

  float p = 0.0f;
#pragma unroll
  for (int j = 0; j < 16; ++j) {
    int t = w * 16 + j;
    p += vals[t] * M[t * 64 + lane];
  }
  red[w][lane] = p;
  if (w == 0) {
    float pb = wave_reduce_add64(ln * uvec[lane]);
    if (lane == 0) qb[bi] = s0v[0] + pb;
  }
  __syncthreads();
  if (w == 0)
    qk[bi * 64 + lane] = cvec[lane] + red[0][lane] + red[1][lane] + red[2][lane] + red[3][lane];
}

// ---------------------------------------------------------------------------
// Init: slots = mu + exp(log_sigma)*noise; zero accumulators + counters.
__global__ __launch_bounds__(256) void k_init(
    const float* __restrict__ noise, const float* __restrict__ mu,
    const float* __restrict__ lsig,
    const float* __restrict__ M, const float* __restrict__ cvec,
    const float* __restrict__ uvec, const float* __restrict__ s0v,
    const float* __restrict__ g_sl, const float* __restrict__ beta_sl,
    float* __restrict__ S_buf, float* __restrict__ qk, float* __restrict__ qb,
    float* __restrict__ acc, float* __restrict__ asum, int* __restrict__ cnt)
{
  __shared__ float vals[64];
  __shared__ float red[4][64];
  int bi = blockIdx.x;
  int tid = threadIdx.x, w = tid >> 6, lane = tid & 63;
  float sl = mu[lane] + __expf(lsig[lane]) * noise[bi * 64 + lane];
  if (w == 0) {
    S_buf[bi * 64 + lane] = sl;
    acc[bi * 64 + lane] = 0.0f;
    if (lane == 0) asum[bi] = 0.0f;
  }
  if (tid == 0 && bi < 64) cnt[bi] = 0;
  slot_qk_256(bi, sl, w, lane, M, cvec, uvec, s0v, g_sl, beta_sl, qk, qb, red, vals);
}

// ---------------------------------------------------------------------------
// Per-slot update (256 threads, lane=d), called by the last block of a batch.
// Reads acc/asum with device-coherent loads.
__device__ void slot_update(int bi, int tid, int w, int lane, int do_next,
    const float* __restrict__ S_in, float* __restrict__ S_out,
    float* __restrict__ acc, float* __restrict__ asum,
    const float* __restrict__ wv, const float* __restrict__ bv,
    const float* __restrict__ w_ih, const float* __restrict__ b_ih,
    const float* __restrict__ w_hh, const float* __restrict__ b_hh,
    const float* __restrict__ w1, const float* __restrict__ b1,
    const float* __restrict__ w2, const float* __restrict__ b2,
    const float* __restrict__ g_ff, const float* __restrict__ beta_ff,
    const float* __restrict__ M, const float* __restrict__ cvec,
    const float* __restrict__ uvec, const float* __restrict__ s0v,
    const float* __restrict__ g_sl, const float* __restrict__ beta_sl,
    float* __restrict__ qk, float* __restrict__ qb,
    float* vals, float (*redm)[4][64])
{
  float* redf = &redm[0][0][0];
  if (tid < 64) {
    float inv = 1.0f / cload(&asum[bi]);
    vals[tid] = cload(&acc[bi * 64 + tid]) * inv;
    if (do_next) {
      acc[bi * 64 + tid] = 0.0f;
      if (tid == 0) asum[bi] = 0.0f;
    }
  }
  float sp = S_in[bi * 64 + lane];
  __syncthreads();

  float pu = 0.0f;
#pragma unroll
  for (int j = 0; j < 16; ++j) {
    int e = w * 16 + j;
    pu += vals[e] * wv[e * 64 + lane];
  }
  redm[0][w][lane] = pu;
  __syncthreads();
  float upd = bv[lane] + redm[0][0][lane] + redm[0][1][lane] + redm[0][2][lane] + redm[0][3][lane];
  __syncthreads();
  if (w == 0) { vals[lane] = upd; vals[64 + lane] = sp; }
  __syncthreads();

  float pr = 0, pz = 0, pn = 0, qr = 0, qz = 0, qn = 0;
#pragma unroll 4
  for (int j = 0; j < 16; ++j) {
    int e = w * 16 + j;
    float uu = vals[e], hh = vals[64 + e];
    const float* wi = w_ih + e * 192;
    const float* wh = w_hh + e * 192;
    pr += uu * wi[lane]; pz += uu * wi[64 + lane]; pn += uu * wi[128 + lane];
    qr += hh * wh[lane]; qz += hh * wh[64 + lane]; qn += hh * wh[128 + lane];
  }
  redm[0][w][lane] = pr; redm[1][w][lane] = pz; redm[2][w][lane] = pn;
  redm[3][w][lane] = qr; redm[4][w][lane] = qz; redm[5][w][lane] = qn;
  __syncthreads();
  float gxr = b_ih[lane], gxz = b_ih[64 + lane], gxn = b_ih[128 + lane];
  float ghr = b_hh[lane], ghz = b_hh[64 + lane], ghn = b_hh[128 + lane];
#pragma unroll
  for (int k = 0; k < 4; ++k) {
    gxr += redm[0][k][lane]; gxz += redm[1][k][lane]; gxn += redm[2][k][lane];
    ghr += redm[3][k][lane]; ghz += redm[4][k][lane]; ghn += redm[5][k][lane];
  }
  float r  = 1.0f / (1.0f + __expf(-(gxr + ghr)));
  float z  = 1.0f / (1.0f + __expf(-(gxz + ghz)));
  float nw = tanhf(gxn + r * ghn);
  float sn = (1.0f - z) * nw + z * sp;

  float s  = wave_reduce_add64(sn);
  float s2 = wave_reduce_add64(sn * sn);
  float mean = s * (1.0f / 64.0f);
  float var  = s2 * (1.0f / 64.0f) - mean * mean;
  float rstd = rsqrtf(var + LN_EPS);
  float ff = (sn - mean) * rstd * g_ff[lane] + beta_ff[lane];
  __syncthreads();
  if (w == 0) vals[lane] = ff;
  __syncthreads();
  {
    int o = tid & 127, half = tid >> 7;
    float ph = 0.0f;
#pragma unroll 8
    for (int j = 0; j < 32; ++j) {
      int e = half * 32 + j;
      ph += vals[e] * w1[e * 128 + o];
    }
    redf[half * 128 + o] = ph;
  }
  __syncthreads();
  if (tid < 128)
    vals[tid] = fmaxf(b1[tid] + redf[tid] + redf[128 + tid], 0.0f);
  __syncthreads();

  float po = 0.0f;
#pragma unroll 8
  for (int j = 0; j < 32; ++j) {
    int t = w * 32 + j;
    po += vals[t] * w2[t * 64 + lane];
  }
  __syncthreads();
  redm[0][w][lane] = po;
  __syncthreads();
  float o = sn + b2[lane] + redm[0][0][lane] + redm[0][1][lane] + redm[0][2][lane] + redm[0][3][lane];
  if (w == 0) S_out[bi * 64 + lane] = o;

  if (do_next)
    slot_qk_256(bi, o, w, lane, M, cvec, uvec, s0v, g_sl, beta_sl, qk, qb,
                (float(*)[64])redf, vals);
  __syncthreads();  // protect vals/redm before next slot reuses them
}

// ---------------------------------------------------------------------------
// Fused main pass + last-block slot update. grid = (CHUNKS, 64), block = 256.
// NOTE: no min-waves clause — R5's __launch_bounds__(256,8) forced VGPR<=64
// and caused ~550 MB/dispatch of scratch spill traffic (VGPR=32 observed).
__global__ __launch_bounds__(256) void k_fused(
    const float* __restrict__ inputs,
    const float* __restrict__ g_in, const float* __restrict__ beta_in,
    float* __restrict__ qk, float* __restrict__ qb,
    float* __restrict__ acc, float* __restrict__ asum,
    const float* __restrict__ S_in, float* __restrict__ S_out,
    const float* __restrict__ wv, const float* __restrict__ bv,
    const float* __restrict__ w_ih, const float* __restrict__ b_ih,
    const float* __restrict__ w_hh, const float* __restrict__ b_hh,
    const float* __restrict__ w1, const float* __restrict__ b1,
    const float* __restrict__ w2, const float* __restrict__ b2,
    const float* __restrict__ g_ff, const float* __restrict__ beta_ff,
    const float* __restrict__ M, const float* __restrict__ cvec,
    const float* __restrict__ uvec, const float* __restrict__ s0v,
    const float* __restrict__ g_sl, const float* __restrict__ beta_sl,
    int* __restrict__ cnt, int do_next)
{
  __shared__ float lds_acc[4][512];
  __shared__ float lds_as[4][8];
  __shared__ float vals[128];
  __shared__ float redm[6][4][64];
  __shared__ int is_last;
  const int b = blockIdx.y;
  const int chunk = blockIdx.x;
  const int tid = threadIdx.x;
  const int lane = tid & 63;
  const int wave = tid >> 6;
  const int p = lane & 15;

  float4 g4  = ((const float4*)g_in)[p];
  float4 be4 = ((const float4*)beta_in)[p];
  float4 qkv[8];
  float qbv[8];
  const float4* qk4 = (const float4*)(qk + b * 512);
#pragma unroll
  for (int i = 0; i < 8; ++i) {
    qkv[i] = qk4[i * 16 + p];
    qbv[i] = qb[b * 8 + i];
  }

  float4 accl[8];
  float asl[8];
#pragma unroll
  for (int i = 0; i < 8; ++i) { accl[i] = make_float4(0.f, 0.f, 0.f, 0.f); asl[i] = 0.f; }

  const float4* in4 = (const float4*)(inputs + (size_t)b * 4096 * 64);
  const int rb0 = chunk * 128 + wave * 4;

  float4 xv = in4[rb0 * 16 + lane];
  for (int it = 0; it < 8; ++it) {
    float4 nxt;
    if (it < 7) nxt = in4[(rb0 + (it + 1) * 16) * 16 + lane];  // prefetch

    float s  = red16(xv.x + xv.y + xv.z + xv.w);
    float s2 = red16(xv.x * xv.x + xv.y * xv.y + xv.z * xv.z + xv.w * xv.w);
    float mean = s * 0.015625f;
    float var  = s2 * 0.015625f - mean * mean;
    float rstd = rsqrtf(var + LN_EPS);
    float4 xln;
    xln.x = (xv.x - mean) * rstd * g4.x + be4.x;
    xln.y = (xv.y - mean) * rstd * g4.y + be4.y;
    xln.z = (xv.z - mean) * rstd * g4.z + be4.z;
    xln.w = (xv.w - mean) * rstd * g4.w + be4.w;

    float dots[8];
#pragma unroll
    for (int i = 0; i < 8; ++i) {
      float d = xln.x * qkv[i].x + xln.y * qkv[i].y + xln.z * qkv[i].z + xln.w * qkv[i].w;
      dots[i] = red16(d) + qbv[i];
    }

    float mx = dots[0];
#pragma unroll
    for (int i = 1; i < 8; ++i) mx = fmaxf(mx, dots[i]);
    float pv[8];
    float ps = 0.0f;
#pragma unroll
    for (int i = 0; i < 8; ++i) { pv[i] = __expf(dots[i] - mx); ps += pv[i]; }
    float inv = __builtin_amdgcn_rcpf(ps);
#pragma unroll
    for (int i = 0; i < 8; ++i) {
      float pp = pv[i] * inv + EPS_ATTN;
      asl[i] += pp;
      accl[i].x += pp * xln.x;
      accl[i].y += pp * xln.y;
      accl[i].z += pp * xln.z;
      accl[i].w += pp * xln.w;
    }
    xv = nxt;
  }

#pragma unroll
  for (int i = 0; i < 8; ++i) {
#pragma unroll
    for (int m = 16; m <= 32; m <<= 1) {
      accl[i].x += __shfl_xor(accl[i].x, m, 64);
      accl[i].y += __shfl_xor(accl[i].y, m, 64);
      accl[i].z += __shfl_xor(accl[i].z, m, 64);
      accl[i].w += __shfl_xor(accl[i].w, m, 64);
      asl[i]    += __shfl_xor(asl[i], m, 64);
    }
  }

  if (lane < 16) {
    float4* dst = (float4*)lds_acc[wave];
#pragma unroll
    for (int i = 0; i < 8; ++i) dst[i * 16 + p] = accl[i];
  }
  if (lane == 0) {
#pragma unroll
    for (int i = 0; i < 8; ++i) lds_as[wave][i] = asl[i];
  }
  __syncthreads();

  for (int f = tid; f < 512; f += 256) {
    float ssum = lds_acc[0][f] + lds_acc[1][f] + lds_acc[2][f] + lds_acc[3][f];
    atomicAdd(&acc[b * 512 + f], ssum);
  }
  if (tid < 8) {
    float ssum = lds_as[0][tid] + lds_as[1][tid] + lds_as[2][tid] + lds_as[3][tid];
    atomicAdd(&asum[b * 8 + tid], ssum);
  }

  // ---- completion detection: last block of this batch does the update ----
  __syncthreads();                 // drains each wave's outstanding atomics
  if (tid == 0) {
    __threadfence();               // release our acc/asum atomics
    int old = atomicAdd(&cnt[b], 1);
    is_last = (old == CHUNKS - 1);
    if (is_last) cnt[b] = 0;       // reset for next dispatch
  }
  __syncthreads();
  if (!is_last) return;
  __threadfence();                 // acquire side

  for (int i = 0; i < 8; ++i) {
    slot_update(b * 8 + i, tid, wave, lane, do_next,
                S_in, S_out, acc, asum, wv, bv, w_ih, b_ih, w_hh, b_hh,
                w1, b1, w2, b2, g_ff, beta_ff, M, cvec, uvec, s0v,
                g_sl, beta_sl, qk, qb, vals, redm);
  }
}

// ---------------------------------------------------------------------------
extern "C" void kernel_launch(void* const* d_in, const int* in_sizes, int n_in,
                              void* d_out, int out_size, void* d_ws, size_t ws_size,
                              hipStream_t stream) {
  const float* inputs  = (const float*)d_in[0];
  const float* noise   = (const float*)d_in[1];
  const float* mu      = (const float*)d_in[2];
  const float* lsig    = (const float*)d_in[3];
  const float* wq      = (const float*)d_in[4];
  const float* bq      = (const float*)d_in[5];
  const float* wk      = (const float*)d_in[6];
  const float* bk      = (const float*)d_in[7];
  const float* wv      = (const float*)d_in[8];
  const float* bv      = (const float*)d_in[9];
  const float* w_ih    = (const float*)d_in[10];
  const float* b_ih    = (const float*)d_in[11];
  const float* w_hh    = (const float*)d_in[12];
  const float* b_hh    = (const float*)d_in[13];
  const float* w1      = (const float*)d_in[14];
  const float* b1      = (const float*)d_in[15];
  const float* w2      = (const float*)d_in[16];
  const float* b2      = (const float*)d_in[17];
  const float* g_in    = (const float*)d_in[18];
  const float* beta_in = (const float*)d_in[19];
  const float* g_sl    = (const float*)d_in[20];
  const float* beta_sl = (const float*)d_in[21];
  const float* g_ff    = (const float*)d_in[22];
  const float* beta_ff = (const float*)d_in[23];

  float* S_buf = (float*)d_ws;        // [64*8*64]
  float* qk    = S_buf + 32768;       // [64*8*64]
  float* qb    = qk + 32768;          // [64*8]
  float* acc   = qb + 512;            // [64*8*64]
  float* asum  = acc + 32768;         // [64*8]
  float* M     = asum + 512;          // [64*64]
  float* cvec  = M + 4096;            // [64]
  float* uvec  = cvec + 64;           // [64]
  float* s0v   = uvec + 64;           // [1]
  int*   cnt   = (int*)(s0v + 1);     // [64]
  float* out   = (float*)d_out;

  k_prep<<<16, 256, 0, stream>>>(wq, wk, bq, bk, M, cvec, uvec, s0v);
  k_init<<<512, 256, 0, stream>>>(noise, mu, lsig, M, cvec, uvec, s0v,
                                  g_sl, beta_sl, S_buf, qk, qb, acc, asum, cnt);

  for (int t = 0; t < 3; ++t) {
    float* dst = (t == 2) ? out : S_buf;
    k_fused<<<dim3(CHUNKS, 64), 256, 0, stream>>>(
        inputs, g_in, beta_in, qk, qb, acc, asum, S_buf, dst,
        wv, bv, w_ih, b_ih, w_hh, b_hh, w1, b1, w2, b2,
        g_ff, beta_ff, M, cvec, uvec, s0v, g_sl, beta_sl,
        cnt, (t == 2) ? 0 : 1);
  }
}

// Round 7
// 638.291 us; speedup vs baseline: 2.5403x; 1.1457x over previous
//
#include <hip/hip_runtime.h>
#include <math.h>

#define LN_EPS 1e-5f
#define EPS_ATTN 1e-8f
#define SCALE 0.125f  // D^-0.5, D=64
#define CHUNKS 32

// ---------------------------------------------------------------------------
__device__ __forceinline__ float wsum64(float v) {
#pragma unroll
  for (int m = 1; m <= 32; m <<= 1) v += __shfl_xor(v, m, 64);
  return v;
}

// 16-lane allreduce sum on the VALU pipe via DPP (no LDS-pipe traffic).
__device__ __forceinline__ float red16(float v) {
  v += __int_as_float(__builtin_amdgcn_update_dpp(0, __float_as_int(v), 0xB1, 0xF, 0xF, true));
  v += __int_as_float(__builtin_amdgcn_update_dpp(0, __float_as_int(v), 0x4E, 0xF, 0xF, true));
  v += __int_as_float(__builtin_amdgcn_update_dpp(0, __float_as_int(v), 0x124, 0xF, 0xF, true));
  v += __int_as_float(__builtin_amdgcn_update_dpp(0, __float_as_int(v), 0x128, 0xF, 0xF, true));
  return v;
}

// device-scope coherent load (bypasses potentially-stale L1 copies)
__device__ __forceinline__ float cload(const float* p) {
  return __hip_atomic_load(p, __ATOMIC_RELAXED, __HIP_MEMORY_SCOPE_AGENT);
}

// ---------------------------------------------------------------------------
// One-time prep: M = scale*wq@wk^T, cvec = scale*bq@wk^T, uvec = scale*wq@bk,
// s0 = scale*bq.bk
__global__ __launch_bounds__(256) void k_prep(
    const float* __restrict__ wq, const float* __restrict__ wk,
    const float* __restrict__ bq, const float* __restrict__ bk,
    float* __restrict__ M, float* __restrict__ cvec,
    float* __restrict__ uvec, float* __restrict__ s0v)
{
  __shared__ float wqs[64 * 64];
  __shared__ float wks[64 * 65];
  int tid = threadIdx.x;
  for (int i = tid; i < 4096; i += 256) wqs[i] = wq[i];
  for (int i = tid; i < 4096; i += 256) wks[(i >> 6) * 65 + (i & 63)] = wk[i];
  __syncthreads();

  int idx = blockIdx.x * 256 + tid;
  int t = idx >> 6, d = idx & 63;
  float a = 0.0f;
#pragma unroll 8
  for (int j = 0; j < 64; ++j) a += wqs[t * 64 + j] * wks[d * 65 + j];
  M[idx] = a * SCALE;

  if (blockIdx.x == 0) {
    if (tid < 64) {
      float cc = 0.0f;
#pragma unroll 8
      for (int j = 0; j < 64; ++j) cc += bq[j] * wks[tid * 65 + j];
      cvec[tid] = cc * SCALE;
    } else if (tid < 128) {
      int t2 = tid - 64;
      float uu = 0.0f;
#pragma unroll 8
      for (int j = 0; j < 64; ++j) uu += wqs[t2 * 64 + j] * bk[j];
      uvec[t2] = uu * SCALE;
    } else if (tid == 128) {
      float ss = 0.0f;
      for (int j = 0; j < 64; ++j) ss += bq[j] * bk[j];
      s0v[0] = ss * SCALE;
    }
  }
}

// ---------------------------------------------------------------------------
// Wave-local slot->qk: one wave, lane=d, value o is this slot's new value.
// All broadcasts via __shfl (uniform index), no barriers anywhere.
__device__ void slot_qk_wave(int bi, float o, int lane,
    const float* __restrict__ M, const float* __restrict__ cvec,
    const float* __restrict__ uvec, const float* __restrict__ s0v,
    const float* __restrict__ g_sl, const float* __restrict__ beta_sl,
    float* __restrict__ qk, float* __restrict__ qb)
{
  float s  = wsum64(o);
  float s2 = wsum64(o * o);
  float mean = s * (1.0f / 64.0f);
  float var  = s2 * (1.0f / 64.0f) - mean * mean;
  float rstd = rsqrtf(var + LN_EPS);
  float ln = (o - mean) * rstd * g_sl[lane] + beta_sl[lane];

  float qv = cvec[lane];
#pragma unroll 8
  for (int t = 0; t < 64; ++t) qv += __shfl(ln, t, 64) * M[t * 64 + lane];
  qk[bi * 64 + lane] = qv;
  float pb = wsum64(ln * uvec[lane]);
  if (lane == 0) qb[bi] = s0v[0] + pb;
}

// ---------------------------------------------------------------------------
// Wave-local full slot update: one wave, lane=d. Zero barriers on the chain.
__device__ void slot_update_wave(int bi, int lane, int do_next,
    const float* __restrict__ S_in, float* __restrict__ S_out,
    float* __restrict__ acc, float* __restrict__ asum,
    const float* __restrict__ wv, const float* __restrict__ bv,
    const float* __restrict__ w_ih, const float* __restrict__ b_ih,
    const float* __restrict__ w_hh, const float* __restrict__ b_hh,
    const float* __restrict__ w1, const float* __restrict__ b1,
    const float* __restrict__ w2, const float* __restrict__ b2,
    const float* __restrict__ g_ff, const float* __restrict__ beta_ff,
    const float* __restrict__ M, const float* __restrict__ cvec,
    const float* __restrict__ uvec, const float* __restrict__ s0v,
    const float* __restrict__ g_sl, const float* __restrict__ beta_sl,
    float* __restrict__ qk, float* __restrict__ qb)
{
  float asv = cload(&asum[bi]);
  float av  = cload(&acc[bi * 64 + lane]);
  float v   = av / asv;
  if (do_next) {
    acc[bi * 64 + lane] = 0.0f;
    if (lane == 0) asum[bi] = 0.0f;
  }
  float sp = S_in[bi * 64 + lane];

  // upd = v @ wv + bv
  float upd = bv[lane];
#pragma unroll 8
  for (int e = 0; e < 64; ++e) upd += __shfl(v, e, 64) * wv[e * 64 + lane];

  // GRU gates (torch order r,z,n)
  float gxr = b_ih[lane], gxz = b_ih[64 + lane], gxn = b_ih[128 + lane];
  float ghr = b_hh[lane], ghz = b_hh[64 + lane], ghn = b_hh[128 + lane];
#pragma unroll 4
  for (int e = 0; e < 64; ++e) {
    float uu = __shfl(upd, e, 64), hh = __shfl(sp, e, 64);
    const float* wi = w_ih + e * 192;
    const float* wh = w_hh + e * 192;
    gxr += uu * wi[lane]; gxz += uu * wi[64 + lane]; gxn += uu * wi[128 + lane];
    ghr += hh * wh[lane]; ghz += hh * wh[64 + lane]; ghn += hh * wh[128 + lane];
  }
  float r  = 1.0f / (1.0f + __expf(-(gxr + ghr)));
  float z  = 1.0f / (1.0f + __expf(-(gxz + ghz)));
  float nw = tanhf(gxn + r * ghn);
  float sn = (1.0f - z) * nw + z * sp;

  // residual MLP: sn + relu(LN(sn)@w1+b1)@w2 + b2
  float s  = wsum64(sn);
  float s2 = wsum64(sn * sn);
  float mean = s * (1.0f / 64.0f);
  float var  = s2 * (1.0f / 64.0f) - mean * mean;
  float rstd = rsqrtf(var + LN_EPS);
  float ff = (sn - mean) * rstd * g_ff[lane] + beta_ff[lane];

  float h1 = b1[lane], h2 = b1[64 + lane];
#pragma unroll 8
  for (int e = 0; e < 64; ++e) {
    float f = __shfl(ff, e, 64);
    h1 += f * w1[e * 128 + lane];
    h2 += f * w1[e * 128 + 64 + lane];
  }
  h1 = fmaxf(h1, 0.0f);
  h2 = fmaxf(h2, 0.0f);

  float o = sn + b2[lane];
#pragma unroll 8
  for (int t = 0; t < 64; ++t) o += __shfl(h1, t, 64) * w2[t * 64 + lane];
#pragma unroll 8
  for (int t = 0; t < 64; ++t) o += __shfl(h2, t, 64) * w2[(64 + t) * 64 + lane];

  S_out[bi * 64 + lane] = o;

  if (do_next)
    slot_qk_wave(bi, o, lane, M, cvec, uvec, s0v, g_sl, beta_sl, qk, qb);
}

// ---------------------------------------------------------------------------
// Init: one wave per slot (block = 64 threads, grid = 512).
__global__ __launch_bounds__(64) void k_init(
    const float* __restrict__ noise, const float* __restrict__ mu,
    const float* __restrict__ lsig,
    const float* __restrict__ M, const float* __restrict__ cvec,
    const float* __restrict__ uvec, const float* __restrict__ s0v,
    const float* __restrict__ g_sl, const float* __restrict__ beta_sl,
    float* __restrict__ S_buf, float* __restrict__ qk, float* __restrict__ qb,
    float* __restrict__ acc, float* __restrict__ asum, int* __restrict__ cnt)
{
  int bi = blockIdx.x;
  int lane = threadIdx.x;
  float sl = mu[lane] + __expf(lsig[lane]) * noise[bi * 64 + lane];
  S_buf[bi * 64 + lane] = sl;
  acc[bi * 64 + lane] = 0.0f;
  if (lane == 0) asum[bi] = 0.0f;
  if (lane == 0 && bi < 64) cnt[bi] = 0;
  slot_qk_wave(bi, sl, lane, M, cvec, uvec, s0v, g_sl, beta_sl, qk, qb);
}

// ---------------------------------------------------------------------------
// Fused main pass + last-block wave-local slot updates.
// grid = (CHUNKS, 64), block = 256.
__global__ __launch_bounds__(256) void k_fused(
    const float* __restrict__ inputs,
    const float* __restrict__ g_in, const float* __restrict__ beta_in,
    float* __restrict__ qk, float* __restrict__ qb,
    float* __restrict__ acc, float* __restrict__ asum,
    const float* __restrict__ S_in, float* __restrict__ S_out,
    const float* __restrict__ wv, const float* __restrict__ bv,
    const float* __restrict__ w_ih, const float* __restrict__ b_ih,
    const float* __restrict__ w_hh, const float* __restrict__ b_hh,
    const float* __restrict__ w1, const float* __restrict__ b1,
    const float* __restrict__ w2, const float* __restrict__ b2,
    const float* __restrict__ g_ff, const float* __restrict__ beta_ff,
    const float* __restrict__ M, const float* __restrict__ cvec,
    const float* __restrict__ uvec, const float* __restrict__ s0v,
    const float* __restrict__ g_sl, const float* __restrict__ beta_sl,
    int* __restrict__ cnt, int do_next)
{
  __shared__ float lds_acc[4][512];
  __shared__ float lds_as[4][8];
  __shared__ int is_last;
  const int b = blockIdx.y;
  const int chunk = blockIdx.x;
  const int tid = threadIdx.x;
  const int lane = tid & 63;
  const int wave = tid >> 6;
  const int p = lane & 15;

  float4 g4  = ((const float4*)g_in)[p];
  float4 be4 = ((const float4*)beta_in)[p];
  float4 qkv[8];
  float qbv[8];
  const float4* qk4 = (const float4*)(qk + b * 512);
#pragma unroll
  for (int i = 0; i < 8; ++i) {
    qkv[i] = qk4[i * 16 + p];
    qbv[i] = qb[b * 8 + i];
  }

  float4 accl[8];
  float asl[8];
#pragma unroll
  for (int i = 0; i < 8; ++i) { accl[i] = make_float4(0.f, 0.f, 0.f, 0.f); asl[i] = 0.f; }

  const float4* in4 = (const float4*)(inputs + (size_t)b * 4096 * 64);
  const int rb0 = chunk * 128 + wave * 4;

  float4 xv = in4[rb0 * 16 + lane];
  for (int it = 0; it < 8; ++it) {
    float4 nxt;
    if (it < 7) nxt = in4[(rb0 + (it + 1) * 16) * 16 + lane];  // prefetch

    float s  = red16(xv.x + xv.y + xv.z + xv.w);
    float s2 = red16(xv.x * xv.x + xv.y * xv.y + xv.z * xv.z + xv.w * xv.w);
    float mean = s * 0.015625f;
    float var  = s2 * 0.015625f - mean * mean;
    float rstd = rsqrtf(var + LN_EPS);
    float4 xln;
    xln.x = (xv.x - mean) * rstd * g4.x + be4.x;
    xln.y = (xv.y - mean) * rstd * g4.y + be4.y;
    xln.z = (xv.z - mean) * rstd * g4.z + be4.z;
    xln.w = (xv.w - mean) * rstd * g4.w + be4.w;

    float dots[8];
#pragma unroll
    for (int i = 0; i < 8; ++i) {
      float d = xln.x * qkv[i].x + xln.y * qkv[i].y + xln.z * qkv[i].z + xln.w * qkv[i].w;
      dots[i] = red16(d) + qbv[i];
    }

    float mx = dots[0];
#pragma unroll
    for (int i = 1; i < 8; ++i) mx = fmaxf(mx, dots[i]);
    float pv[8];
    float ps = 0.0f;
#pragma unroll
    for (int i = 0; i < 8; ++i) { pv[i] = __expf(dots[i] - mx); ps += pv[i]; }
    float inv = __builtin_amdgcn_rcpf(ps);
#pragma unroll
    for (int i = 0; i < 8; ++i) {
      float pp = pv[i] * inv + EPS_ATTN;
      asl[i] += pp;
      accl[i].x += pp * xln.x;
      accl[i].y += pp * xln.y;
      accl[i].z += pp * xln.z;
      accl[i].w += pp * xln.w;
    }
    xv = nxt;
  }

#pragma unroll
  for (int i = 0; i < 8; ++i) {
#pragma unroll
    for (int m = 16; m <= 32; m <<= 1) {
      accl[i].x += __shfl_xor(accl[i].x, m, 64);
      accl[i].y += __shfl_xor(accl[i].y, m, 64);
      accl[i].z += __shfl_xor(accl[i].z, m, 64);
      accl[i].w += __shfl_xor(accl[i].w, m, 64);
      asl[i]    += __shfl_xor(asl[i], m, 64);
    }
  }

  if (lane < 16) {
    float4* dst = (float4*)lds_acc[wave];
#pragma unroll
    for (int i = 0; i < 8; ++i) dst[i * 16 + p] = accl[i];
  }
  if (lane == 0) {
#pragma unroll
    for (int i = 0; i < 8; ++i) lds_as[wave][i] = asl[i];
  }
  __syncthreads();

  for (int f = tid; f < 512; f += 256) {
    float ssum = lds_acc[0][f] + lds_acc[1][f] + lds_acc[2][f] + lds_acc[3][f];
    atomicAdd(&acc[b * 512 + f], ssum);
  }
  if (tid < 8) {
    float ssum = lds_as[0][tid] + lds_as[1][tid] + lds_as[2][tid] + lds_as[3][tid];
    atomicAdd(&asum[b * 8 + tid], ssum);
  }

  // ---- completion detection: last block of this batch does the updates ----
  __syncthreads();                 // drains each wave's outstanding atomics
  if (tid == 0) {
    __threadfence();               // release our acc/asum atomics
    int old = atomicAdd(&cnt[b], 1);
    is_last = (old == CHUNKS - 1);
    if (is_last) cnt[b] = 0;       // reset for next dispatch
  }
  __syncthreads();
  if (!is_last) return;
  __threadfence();                 // acquire side

  // 8 slots over 4 waves, 2 rounds, fully wave-local (no barriers)
  for (int i = wave; i < 8; i += 4) {
    slot_update_wave(b * 8 + i, lane, do_next,
                     S_in, S_out, acc, asum, wv, bv, w_ih, b_ih, w_hh, b_hh,
                     w1, b1, w2, b2, g_ff, beta_ff, M, cvec, uvec, s0v,
                     g_sl, beta_sl, qk, qb);
  }
}

// ---------------------------------------------------------------------------
extern "C" void kernel_launch(void* const* d_in, const int* in_sizes, int n_in,
                              void* d_out, int out_size, void* d_ws, size_t ws_size,
                              hipStream_t stream) {
  const float* inputs  = (const float*)d_in[0];
  const float* noise   = (const float*)d_in[1];
  const float* mu      = (const float*)d_in[2];
  const float* lsig    = (const float*)d_in[3];
  const float* wq      = (const float*)d_in[4];
  const float* bq      = (const float*)d_in[5];
  const float* wk      = (const float*)d_in[6];
  const float* bk      = (const float*)d_in[7];
  const float* wv      = (const float*)d_in[8];
  const float* bv      = (const float*)d_in[9];
  const float* w_ih    = (const float*)d_in[10];
  const float* b_ih    = (const float*)d_in[11];
  const float* w_hh    = (const float*)d_in[12];
  const float* b_hh    = (const float*)d_in[13];
  const float* w1      = (const float*)d_in[14];
  const float* b1      = (const float*)d_in[15];
  const float* w2      = (const float*)d_in[16];
  const float* b2      = (const float*)d_in[17];
  const float* g_in    = (const float*)d_in[18];
  const float* beta_in = (const float*)d_in[19];
  const float* g_sl    = (const float*)d_in[20];
  const float* beta_sl = (const float*)d_in[21];
  const float* g_ff    = (const float*)d_in[22];
  const float* beta_ff = (const float*)d_in[23];

  float* S_buf = (float*)d_ws;        // [64*8*64]
  float* qk    = S_buf + 32768;       // [64*8*64]
  float* qb    = qk + 32768;          // [64*8]
  float* acc   = qb + 512;            // [64*8*64]
  float* asum  = acc + 32768;         // [64*8]
  float* M     = asum + 512;          // [64*64]
  float* cvec  = M + 4096;            // [64]
  float* uvec  = cvec + 64;           // [64]
  float* s0v   = uvec + 64;           // [1]
  int*   cnt   = (int*)(s0v + 1);     // [64]
  float* out   = (float*)d_out;

  k_prep<<<16, 256, 0, stream>>>(wq, wk, bq, bk, M, cvec, uvec, s0v);
  k_init<<<512, 64, 0, stream>>>(noise, mu, lsig, M, cvec, uvec, s0v,
                                 g_sl, beta_sl, S_buf, qk, qb, acc, asum, cnt);

  for (int t = 0; t < 3; ++t) {
    float* dst = (t == 2) ? out : S_buf;
    k_fused<<<dim3(CHUNKS, 64), 256, 0, stream>>>(
        inputs, g_in, beta_in, qk, qb, acc, asum, S_buf, dst,
        wv, bv, w_ih, b_ih, w_hh, b_hh, w1, b1, w2, b2,
        g_ff, beta_ff, M, cvec, uvec, s0v, g_sl, beta_sl,
        cnt, (t == 2) ? 0 : 1);
  }
}

// Round 8
// 387.597 us; speedup vs baseline: 4.1833x; 1.6468x over previous
//
#include <hip/hip_runtime.h>
#include <math.h>

#define LN_EPS 1e-5f
#define EPS_ATTN 1e-8f
#define SCALE 0.125f  // D^-0.5, D=64
#define CHUNKS 32

// ---------------------------------------------------------------------------
__device__ __forceinline__ float wsum64(float v) {
#pragma unroll
  for (int m = 1; m <= 32; m <<= 1) v += __shfl_xor(v, m, 64);
  return v;
}

// 16-lane allreduce sum on the VALU pipe via DPP (no LDS-pipe traffic).
__device__ __forceinline__ float red16(float v) {
  v += __int_as_float(__builtin_amdgcn_update_dpp(0, __float_as_int(v), 0xB1, 0xF, 0xF, true));
  v += __int_as_float(__builtin_amdgcn_update_dpp(0, __float_as_int(v), 0x4E, 0xF, 0xF, true));
  v += __int_as_float(__builtin_amdgcn_update_dpp(0, __float_as_int(v), 0x124, 0xF, 0xF, true));
  v += __int_as_float(__builtin_amdgcn_update_dpp(0, __float_as_int(v), 0x128, 0xF, 0xF, true));
  return v;
}

// agent-scope coherent load (bypasses non-coherent L1/L2; reads the
// coherence point directly — no buffer_inv needed on the acquire path)
__device__ __forceinline__ float cload(const float* p) {
  return __hip_atomic_load(p, __ATOMIC_RELAXED, __HIP_MEMORY_SCOPE_AGENT);
}

// ---------------------------------------------------------------------------
// One-time prep: M = scale*wq@wk^T, cvec = scale*bq@wk^T, uvec = scale*wq@bk,
// s0 = scale*bq.bk
__global__ __launch_bounds__(256) void k_prep(
    const float* __restrict__ wq, const float* __restrict__ wk,
    const float* __restrict__ bq, const float* __restrict__ bk,
    float* __restrict__ M, float* __restrict__ cvec,
    float* __restrict__ uvec, float* __restrict__ s0v)
{
  __shared__ float wqs[64 * 64];
  __shared__ float wks[64 * 65];
  int tid = threadIdx.x;
  for (int i = tid; i < 4096; i += 256) wqs[i] = wq[i];
  for (int i = tid; i < 4096; i += 256) wks[(i >> 6) * 65 + (i & 63)] = wk[i];
  __syncthreads();

  int idx = blockIdx.x * 256 + tid;
  int t = idx >> 6, d = idx & 63;
  float a = 0.0f;
#pragma unroll 8
  for (int j = 0; j < 64; ++j) a += wqs[t * 64 + j] * wks[d * 65 + j];
  M[idx] = a * SCALE;

  if (blockIdx.x == 0) {
    if (tid < 64) {
      float cc = 0.0f;
#pragma unroll 8
      for (int j = 0; j < 64; ++j) cc += bq[j] * wks[tid * 65 + j];
      cvec[tid] = cc * SCALE;
    } else if (tid < 128) {
      int t2 = tid - 64;
      float uu = 0.0f;
#pragma unroll 8
      for (int j = 0; j < 64; ++j) uu += wqs[t2 * 64 + j] * bk[j];
      uvec[t2] = uu * SCALE;
    } else if (tid == 128) {
      float ss = 0.0f;
      for (int j = 0; j < 64; ++j) ss += bq[j] * bk[j];
      s0v[0] = ss * SCALE;
    }
  }
}

// ---------------------------------------------------------------------------
// Wave-local slot->qk: one wave, lane=d, value o is this slot's new value.
__device__ void slot_qk_wave(int bi, float o, int lane,
    const float* __restrict__ M, const float* __restrict__ cvec,
    const float* __restrict__ uvec, const float* __restrict__ s0v,
    const float* __restrict__ g_sl, const float* __restrict__ beta_sl,
    float* __restrict__ qk, float* __restrict__ qb)
{
  float s  = wsum64(o);
  float s2 = wsum64(o * o);
  float mean = s * (1.0f / 64.0f);
  float var  = s2 * (1.0f / 64.0f) - mean * mean;
  float rstd = rsqrtf(var + LN_EPS);
  float ln = (o - mean) * rstd * g_sl[lane] + beta_sl[lane];

  float qv = cvec[lane];
#pragma unroll 8
  for (int t = 0; t < 64; ++t) qv += __shfl(ln, t, 64) * M[t * 64 + lane];
  qk[bi * 64 + lane] = qv;
  float pb = wsum64(ln * uvec[lane]);
  if (lane == 0) qb[bi] = s0v[0] + pb;
}

// ---------------------------------------------------------------------------
// Wave-local full slot update: one wave, lane=d. Zero barriers on the chain.
__device__ void slot_update_wave(int bi, int lane, int do_next,
    const float* __restrict__ S_in, float* __restrict__ S_out,
    float* __restrict__ acc, float* __restrict__ asum,
    const float* __restrict__ wv, const float* __restrict__ bv,
    const float* __restrict__ w_ih, const float* __restrict__ b_ih,
    const float* __restrict__ w_hh, const float* __restrict__ b_hh,
    const float* __restrict__ w1, const float* __restrict__ b1,
    const float* __restrict__ w2, const float* __restrict__ b2,
    const float* __restrict__ g_ff, const float* __restrict__ beta_ff,
    const float* __restrict__ M, const float* __restrict__ cvec,
    const float* __restrict__ uvec, const float* __restrict__ s0v,
    const float* __restrict__ g_sl, const float* __restrict__ beta_sl,
    float* __restrict__ qk, float* __restrict__ qb)
{
  float asv = cload(&asum[bi]);
  float av  = cload(&acc[bi * 64 + lane]);
  float v   = av / asv;
  if (do_next) {
    acc[bi * 64 + lane] = 0.0f;
    if (lane == 0) asum[bi] = 0.0f;
  }
  float sp = S_in[bi * 64 + lane];

  // upd = v @ wv + bv
  float upd = bv[lane];
#pragma unroll 8
  for (int e = 0; e < 64; ++e) upd += __shfl(v, e, 64) * wv[e * 64 + lane];

  // GRU gates (torch order r,z,n)
  float gxr = b_ih[lane], gxz = b_ih[64 + lane], gxn = b_ih[128 + lane];
  float ghr = b_hh[lane], ghz = b_hh[64 + lane], ghn = b_hh[128 + lane];
#pragma unroll 4
  for (int e = 0; e < 64; ++e) {
    float uu = __shfl(upd, e, 64), hh = __shfl(sp, e, 64);
    const float* wi = w_ih + e * 192;
    const float* wh = w_hh + e * 192;
    gxr += uu * wi[lane]; gxz += uu * wi[64 + lane]; gxn += uu * wi[128 + lane];
    ghr += hh * wh[lane]; ghz += hh * wh[64 + lane]; ghn += hh * wh[128 + lane];
  }
  float r  = 1.0f / (1.0f + __expf(-(gxr + ghr)));
  float z  = 1.0f / (1.0f + __expf(-(gxz + ghz)));
  float nw = tanhf(gxn + r * ghn);
  float sn = (1.0f - z) * nw + z * sp;

  // residual MLP: sn + relu(LN(sn)@w1+b1)@w2 + b2
  float s  = wsum64(sn);
  float s2 = wsum64(sn * sn);
  float mean = s * (1.0f / 64.0f);
  float var  = s2 * (1.0f / 64.0f) - mean * mean;
  float rstd = rsqrtf(var + LN_EPS);
  float ff = (sn - mean) * rstd * g_ff[lane] + beta_ff[lane];

  float h1 = b1[lane], h2 = b1[64 + lane];
#pragma unroll 8
  for (int e = 0; e < 64; ++e) {
    float f = __shfl(ff, e, 64);
    h1 += f * w1[e * 128 + lane];
    h2 += f * w1[e * 128 + 64 + lane];
  }
  h1 = fmaxf(h1, 0.0f);
  h2 = fmaxf(h2, 0.0f);

  float o = sn + b2[lane];
#pragma unroll 8
  for (int t = 0; t < 64; ++t) o += __shfl(h1, t, 64) * w2[t * 64 + lane];
#pragma unroll 8
  for (int t = 0; t < 64; ++t) o += __shfl(h2, t, 64) * w2[(64 + t) * 64 + lane];

  S_out[bi * 64 + lane] = o;

  if (do_next)
    slot_qk_wave(bi, o, lane, M, cvec, uvec, s0v, g_sl, beta_sl, qk, qb);
}

// ---------------------------------------------------------------------------
// Init: one wave per slot (block = 64 threads, grid = 512).
__global__ __launch_bounds__(64) void k_init(
    const float* __restrict__ noise, const float* __restrict__ mu,
    const float* __restrict__ lsig,
    const float* __restrict__ M, const float* __restrict__ cvec,
    const float* __restrict__ uvec, const float* __restrict__ s0v,
    const float* __restrict__ g_sl, const float* __restrict__ beta_sl,
    float* __restrict__ S_buf, float* __restrict__ qk, float* __restrict__ qb,
    float* __restrict__ acc, float* __restrict__ asum, int* __restrict__ cnt)
{
  int bi = blockIdx.x;
  int lane = threadIdx.x;
  float sl = mu[lane] + __expf(lsig[lane]) * noise[bi * 64 + lane];
  S_buf[bi * 64 + lane] = sl;
  acc[bi * 64 + lane] = 0.0f;
  if (lane == 0) asum[bi] = 0.0f;
  if (lane == 0 && bi < 64) cnt[bi] = 0;
  slot_qk_wave(bi, sl, lane, M, cvec, uvec, s0v, g_sl, beta_sl, qk, qb);
}

// ---------------------------------------------------------------------------
// Fused main pass + last-block wave-local slot updates.
// grid = (CHUNKS, 64), block = 256.
//
// NO __threadfence() in the completion protocol: on multi-XCD gfx950 an
// agent-scope fence lowers to buffer_wbl2/buffer_inv (full L2 sweep) — 2048
// of them cost ~170 us (R6/R7 evidence). They are not needed here: ALL
// cross-block traffic in-dispatch is device-scope atomics; __syncthreads()
// lowers with s_waitcnt vmcnt(0), so each block's acc/asum atomics are acked
// at the coherence point before its cnt atomic issues, and the tail reads
// acc/asum via L1/L2-bypassing atomic loads (cload).
__global__ __launch_bounds__(256) void k_fused(
    const float* __restrict__ inputs,
    const float* __restrict__ g_in, const float* __restrict__ beta_in,
    float* __restrict__ qk, float* __restrict__ qb,
    float* __restrict__ acc, float* __restrict__ asum,
    const float* __restrict__ S_in, float* __restrict__ S_out,
    const float* __restrict__ wv, const float* __restrict__ bv,
    const float* __restrict__ w_ih, const float* __restrict__ b_ih,
    const float* __restrict__ w_hh, const float* __restrict__ b_hh,
    const float* __restrict__ w1, const float* __restrict__ b1,
    const float* __restrict__ w2, const float* __restrict__ b2,
    const float* __restrict__ g_ff, const float* __restrict__ beta_ff,
    const float* __restrict__ M, const float* __restrict__ cvec,
    const float* __restrict__ uvec, const float* __restrict__ s0v,
    const float* __restrict__ g_sl, const float* __restrict__ beta_sl,
    int* __restrict__ cnt, int do_next)
{
  __shared__ float lds_acc[4][512];
  __shared__ float lds_as[4][8];
  __shared__ int is_last;
  const int b = blockIdx.y;
  const int chunk = blockIdx.x;
  const int tid = threadIdx.x;
  const int lane = tid & 63;
  const int wave = tid >> 6;
  const int p = lane & 15;

  float4 g4  = ((const float4*)g_in)[p];
  float4 be4 = ((const float4*)beta_in)[p];
  float4 qkv[8];
  float qbv[8];
  const float4* qk4 = (const float4*)(qk + b * 512);
#pragma unroll
  for (int i = 0; i < 8; ++i) {
    qkv[i] = qk4[i * 16 + p];
    qbv[i] = qb[b * 8 + i];
  }

  float4 accl[8];
  float asl[8];
#pragma unroll
  for (int i = 0; i < 8; ++i) { accl[i] = make_float4(0.f, 0.f, 0.f, 0.f); asl[i] = 0.f; }

  const float4* in4 = (const float4*)(inputs + (size_t)b * 4096 * 64);
  const int rb0 = chunk * 128 + wave * 4;

  float4 xv = in4[rb0 * 16 + lane];
  for (int it = 0; it < 8; ++it) {
    float4 nxt;
    if (it < 7) nxt = in4[(rb0 + (it + 1) * 16) * 16 + lane];  // prefetch

    float s  = red16(xv.x + xv.y + xv.z + xv.w);
    float s2 = red16(xv.x * xv.x + xv.y * xv.y + xv.z * xv.z + xv.w * xv.w);
    float mean = s * 0.015625f;
    float var  = s2 * 0.015625f - mean * mean;
    float rstd = rsqrtf(var + LN_EPS);
    float4 xln;
    xln.x = (xv.x - mean) * rstd * g4.x + be4.x;
    xln.y = (xv.y - mean) * rstd * g4.y + be4.y;
    xln.z = (xv.z - mean) * rstd * g4.z + be4.z;
    xln.w = (xv.w - mean) * rstd * g4.w + be4.w;

    float dots[8];
#pragma unroll
    for (int i = 0; i < 8; ++i) {
      float d = xln.x * qkv[i].x + xln.y * qkv[i].y + xln.z * qkv[i].z + xln.w * qkv[i].w;
      dots[i] = red16(d) + qbv[i];
    }

    float mx = dots[0];
#pragma unroll
    for (int i = 1; i < 8; ++i) mx = fmaxf(mx, dots[i]);
    float pv[8];
    float ps = 0.0f;
#pragma unroll
    for (int i = 0; i < 8; ++i) { pv[i] = __expf(dots[i] - mx); ps += pv[i]; }
    float inv = __builtin_amdgcn_rcpf(ps);
#pragma unroll
    for (int i = 0; i < 8; ++i) {
      float pp = pv[i] * inv + EPS_ATTN;
      asl[i] += pp;
      accl[i].x += pp * xln.x;
      accl[i].y += pp * xln.y;
      accl[i].z += pp * xln.z;
      accl[i].w += pp * xln.w;
    }
    xv = nxt;
  }

#pragma unroll
  for (int i = 0; i < 8; ++i) {
#pragma unroll
    for (int m = 16; m <= 32; m <<= 1) {
      accl[i].x += __shfl_xor(accl[i].x, m, 64);
      accl[i].y += __shfl_xor(accl[i].y, m, 64);
      accl[i].z += __shfl_xor(accl[i].z, m, 64);
      accl[i].w += __shfl_xor(accl[i].w, m, 64);
      asl[i]    += __shfl_xor(asl[i], m, 64);
    }
  }

  if (lane < 16) {
    float4* dst = (float4*)lds_acc[wave];
#pragma unroll
    for (int i = 0; i < 8; ++i) dst[i * 16 + p] = accl[i];
  }
  if (lane == 0) {
#pragma unroll
    for (int i = 0; i < 8; ++i) lds_as[wave][i] = asl[i];
  }
  __syncthreads();

  for (int f = tid; f < 512; f += 256) {
    float ssum = lds_acc[0][f] + lds_acc[1][f] + lds_acc[2][f] + lds_acc[3][f];
    atomicAdd(&acc[b * 512 + f], ssum);
  }
  if (tid < 8) {
    float ssum = lds_as[0][tid] + lds_as[1][tid] + lds_as[2][tid] + lds_as[3][tid];
    atomicAdd(&asum[b * 8 + tid], ssum);
  }

  // ---- completion detection (fence-free; see kernel comment) ----
  __syncthreads();   // lowers with s_waitcnt vmcnt(0): acc/asum atomics acked
  if (tid == 0) {
    int old = atomicAdd(&cnt[b], 1);
    is_last = (old == CHUNKS - 1);
    if (is_last) cnt[b] = 0;       // reset for next dispatch
  }
  __syncthreads();
  if (!is_last) return;

  // 8 slots over 4 waves, 2 rounds, fully wave-local (no barriers)
  for (int i = wave; i < 8; i += 4) {
    slot_update_wave(b * 8 + i, lane, do_next,
                     S_in, S_out, acc, asum, wv, bv, w_ih, b_ih, w_hh, b_hh,
                     w1, b1, w2, b2, g_ff, beta_ff, M, cvec, uvec, s0v,
                     g_sl, beta_sl, qk, qb);
  }
}

// ---------------------------------------------------------------------------
extern "C" void kernel_launch(void* const* d_in, const int* in_sizes, int n_in,
                              void* d_out, int out_size, void* d_ws, size_t ws_size,
                              hipStream_t stream) {
  const float* inputs  = (const float*)d_in[0];
  const float* noise   = (const float*)d_in[1];
  const float* mu      = (const float*)d_in[2];
  const float* lsig    = (const float*)d_in[3];
  const float* wq      = (const float*)d_in[4];
  const float* bq      = (const float*)d_in[5];
  const float* wk      = (const float*)d_in[6];
  const float* bk      = (const float*)d_in[7];
  const float* wv      = (const float*)d_in[8];
  const float* bv      = (const float*)d_in[9];
  const float* w_ih    = (const float*)d_in[10];
  const float* b_ih    = (const float*)d_in[11];
  const float* w_hh    = (const float*)d_in[12];
  const float* b_hh    = (const float*)d_in[13];
  const float* w1      = (const float*)d_in[14];
  const float* b1      = (const float*)d_in[15];
  const float* w2      = (const float*)d_in[16];
  const float* b2      = (const float*)d_in[17];
  const float* g_in    = (const float*)d_in[18];
  const float* beta_in = (const float*)d_in[19];
  const float* g_sl    = (const float*)d_in[20];
  const float* beta_sl = (const float*)d_in[21];
  const float* g_ff    = (const float*)d_in[22];
  const float* beta_ff = (const float*)d_in[23];

  float* S_buf = (float*)d_ws;        // [64*8*64]
  float* qk    = S_buf + 32768;       // [64*8*64]
  float* qb    = qk + 32768;          // [64*8]
  float* acc   = qb + 512;            // [64*8*64]
  float* asum  = acc + 32768;         // [64*8]
  float* M     = asum + 512;          // [64*64]
  float* cvec  = M + 4096;            // [64]
  float* uvec  = cvec + 64;           // [64]
  float* s0v   = uvec + 64;           // [1]
  int*   cnt   = (int*)(s0v + 1);     // [64]
  float* out   = (float*)d_out;

  k_prep<<<16, 256, 0, stream>>>(wq, wk, bq, bk, M, cvec, uvec, s0v);
  k_init<<<512, 64, 0, stream>>>(noise, mu, lsig, M, cvec, uvec, s0v,
                                 g_sl, beta_sl, S_buf, qk, qb, acc, asum, cnt);

  for (int t = 0; t < 3; ++t) {
    float* dst = (t == 2) ? out : S_buf;
    k_fused<<<dim3(CHUNKS, 64), 256, 0, stream>>>(
        inputs, g_in, beta_in, qk, qb, acc, asum, S_buf, dst,
        wv, bv, w_ih, b_ih, w_hh, b_hh, w1, b1, w2, b2,
        g_ff, beta_ff, M, cvec, uvec, s0v, g_sl, beta_sl,
        cnt, (t == 2) ? 0 : 1);
  }
}

// Round 9
// 242.982 us; speedup vs baseline: 6.6731x; 1.5952x over previous
//
#include <hip/hip_runtime.h>
#include <math.h>

#define LN_EPS 1e-5f
#define EPS_ATTN 1e-8f
#define SCALE 0.125f  // D^-0.5, D=64
#define CHUNKS 32

// ---------------------------------------------------------------------------
__device__ __forceinline__ float wsum64(float v) {
#pragma unroll
  for (int m = 1; m <= 32; m <<= 1) v += __shfl_xor(v, m, 64);
  return v;
}

// 16-lane allreduce sum on the VALU pipe via DPP (no LDS-pipe traffic).
__device__ __forceinline__ float red16(float v) {
  v += __int_as_float(__builtin_amdgcn_update_dpp(0, __float_as_int(v), 0xB1, 0xF, 0xF, true));
  v += __int_as_float(__builtin_amdgcn_update_dpp(0, __float_as_int(v), 0x4E, 0xF, 0xF, true));
  v += __int_as_float(__builtin_amdgcn_update_dpp(0, __float_as_int(v), 0x124, 0xF, 0xF, true));
  v += __int_as_float(__builtin_amdgcn_update_dpp(0, __float_as_int(v), 0x128, 0xF, 0xF, true));
  return v;
}

// ---------------------------------------------------------------------------
// One-time prep: M = scale*wq@wk^T, cvec = scale*bq@wk^T, uvec = scale*wq@bk,
// s0 = scale*bq.bk
__global__ __launch_bounds__(256) void k_prep(
    const float* __restrict__ wq, const float* __restrict__ wk,
    const float* __restrict__ bq, const float* __restrict__ bk,
    float* __restrict__ M, float* __restrict__ cvec,
    float* __restrict__ uvec, float* __restrict__ s0v)
{
  __shared__ float wqs[64 * 64];
  __shared__ float wks[64 * 65];
  int tid = threadIdx.x;
  for (int i = tid; i < 4096; i += 256) wqs[i] = wq[i];
  for (int i = tid; i < 4096; i += 256) wks[(i >> 6) * 65 + (i & 63)] = wk[i];
  __syncthreads();

  int idx = blockIdx.x * 256 + tid;
  int t = idx >> 6, d = idx & 63;
  float a = 0.0f;
#pragma unroll 8
  for (int j = 0; j < 64; ++j) a += wqs[t * 64 + j] * wks[d * 65 + j];
  M[idx] = a * SCALE;

  if (blockIdx.x == 0) {
    if (tid < 64) {
      float cc = 0.0f;
#pragma unroll 8
      for (int j = 0; j < 64; ++j) cc += bq[j] * wks[tid * 65 + j];
      cvec[tid] = cc * SCALE;
    } else if (tid < 128) {
      int t2 = tid - 64;
      float uu = 0.0f;
#pragma unroll 8
      for (int j = 0; j < 64; ++j) uu += wqs[t2 * 64 + j] * bk[j];
      uvec[t2] = uu * SCALE;
    } else if (tid == 128) {
      float ss = 0.0f;
      for (int j = 0; j < 64; ++j) ss += bq[j] * bk[j];
      s0v[0] = ss * SCALE;
    }
  }
}

// ---------------------------------------------------------------------------
// Wave-local slot->qk: one wave, lane=d, value o is this slot's new value.
// Full unroll: all 64 M-loads issue before the first dependent use.
__device__ void slot_qk_wave(int bi, float o, int lane,
    const float* __restrict__ M, const float* __restrict__ cvec,
    const float* __restrict__ uvec, const float* __restrict__ s0v,
    const float* __restrict__ g_sl, const float* __restrict__ beta_sl,
    float* __restrict__ qk, float* __restrict__ qb)
{
  float s  = wsum64(o);
  float s2 = wsum64(o * o);
  float mean = s * (1.0f / 64.0f);
  float var  = s2 * (1.0f / 64.0f) - mean * mean;
  float rstd = rsqrtf(var + LN_EPS);
  float ln = (o - mean) * rstd * g_sl[lane] + beta_sl[lane];

  float qv = cvec[lane];
#pragma unroll
  for (int t = 0; t < 64; ++t) qv += __shfl(ln, t, 64) * M[t * 64 + lane];
  qk[bi * 64 + lane] = qv;
  float pb = wsum64(ln * uvec[lane]);
  if (lane == 0) qb[bi] = s0v[0] + pb;
}

// ---------------------------------------------------------------------------
// Wave-local full slot update: one wave, lane=d. Zero barriers on the chain.
// Deep unrolls so each matvec's loads pipeline in one latency group.
__device__ void slot_update_wave(int bi, int lane, int do_next,
    const float* __restrict__ S_in, float* __restrict__ S_out,
    float* __restrict__ acc, float* __restrict__ asum,
    const float* __restrict__ wv, const float* __restrict__ bv,
    const float* __restrict__ w_ih, const float* __restrict__ b_ih,
    const float* __restrict__ w_hh, const float* __restrict__ b_hh,
    const float* __restrict__ w1, const float* __restrict__ b1,
    const float* __restrict__ w2, const float* __restrict__ b2,
    const float* __restrict__ g_ff, const float* __restrict__ beta_ff,
    const float* __restrict__ M, const float* __restrict__ cvec,
    const float* __restrict__ uvec, const float* __restrict__ s0v,
    const float* __restrict__ g_sl, const float* __restrict__ beta_sl,
    float* __restrict__ qk, float* __restrict__ qb)
{
  // kernel-boundary coherence: acc/asum written by previous dispatch's
  // atomics are visible to plain loads here.
  float asv = asum[bi];
  float av  = acc[bi * 64 + lane];
  float v   = av / asv;
  if (do_next) {
    acc[bi * 64 + lane] = 0.0f;
    if (lane == 0) asum[bi] = 0.0f;
  }
  float sp = S_in[bi * 64 + lane];

  // upd = v @ wv + bv  (full unroll: 64 loads in flight)
  float upd = bv[lane];
#pragma unroll
  for (int e = 0; e < 64; ++e) upd += __shfl(v, e, 64) * wv[e * 64 + lane];

  // GRU gates (torch order r,z,n) — 6 streams, unroll 16 => 96 loads/group
  float gxr = b_ih[lane], gxz = b_ih[64 + lane], gxn = b_ih[128 + lane];
  float ghr = b_hh[lane], ghz = b_hh[64 + lane], ghn = b_hh[128 + lane];
#pragma unroll 16
  for (int e = 0; e < 64; ++e) {
    float uu = __shfl(upd, e, 64), hh = __shfl(sp, e, 64);
    const float* wi = w_ih + e * 192;
    const float* wh = w_hh + e * 192;
    gxr += uu * wi[lane]; gxz += uu * wi[64 + lane]; gxn += uu * wi[128 + lane];
    ghr += hh * wh[lane]; ghz += hh * wh[64 + lane]; ghn += hh * wh[128 + lane];
  }
  float r  = 1.0f / (1.0f + __expf(-(gxr + ghr)));
  float z  = 1.0f / (1.0f + __expf(-(gxz + ghz)));
  float nw = tanhf(gxn + r * ghn);
  float sn = (1.0f - z) * nw + z * sp;

  // residual MLP: sn + relu(LN(sn)@w1+b1)@w2 + b2
  float s  = wsum64(sn);
  float s2 = wsum64(sn * sn);
  float mean = s * (1.0f / 64.0f);
  float var  = s2 * (1.0f / 64.0f) - mean * mean;
  float rstd = rsqrtf(var + LN_EPS);
  float ff = (sn - mean) * rstd * g_ff[lane] + beta_ff[lane];

  float h1 = b1[lane], h2 = b1[64 + lane];
#pragma unroll
  for (int e = 0; e < 64; ++e) {
    float f = __shfl(ff, e, 64);
    h1 += f * w1[e * 128 + lane];
    h2 += f * w1[e * 128 + 64 + lane];
  }
  h1 = fmaxf(h1, 0.0f);
  h2 = fmaxf(h2, 0.0f);

  float o = sn + b2[lane];
#pragma unroll
  for (int t = 0; t < 64; ++t) o += __shfl(h1, t, 64) * w2[t * 64 + lane];
#pragma unroll
  for (int t = 0; t < 64; ++t) o += __shfl(h2, t, 64) * w2[(64 + t) * 64 + lane];

  S_out[bi * 64 + lane] = o;

  if (do_next)
    slot_qk_wave(bi, o, lane, M, cvec, uvec, s0v, g_sl, beta_sl, qk, qb);
}

// ---------------------------------------------------------------------------
// Init: one wave per slot (block = 64 threads, grid = 512).
__global__ __launch_bounds__(64) void k_init(
    const float* __restrict__ noise, const float* __restrict__ mu,
    const float* __restrict__ lsig,
    const float* __restrict__ M, const float* __restrict__ cvec,
    const float* __restrict__ uvec, const float* __restrict__ s0v,
    const float* __restrict__ g_sl, const float* __restrict__ beta_sl,
    float* __restrict__ S_buf, float* __restrict__ qk, float* __restrict__ qb,
    float* __restrict__ acc, float* __restrict__ asum)
{
  int bi = blockIdx.x;
  int lane = threadIdx.x;
  float sl = mu[lane] + __expf(lsig[lane]) * noise[bi * 64 + lane];
  S_buf[bi * 64 + lane] = sl;
  acc[bi * 64 + lane] = 0.0f;
  if (lane == 0) asum[bi] = 0.0f;
  slot_qk_wave(bi, sl, lane, M, cvec, uvec, s0v, g_sl, beta_sl, qk, qb);
}

// ---------------------------------------------------------------------------
// Per-slot update: 512 blocks x 64 lanes, fully parallel wave-local chains.
// All 512 waves read the same ~150 KB of weights -> L2 broadcast after
// first touch.
__global__ __launch_bounds__(64) void k_update(
    const float* __restrict__ S_in, float* __restrict__ S_out,
    float* __restrict__ acc, float* __restrict__ asum,
    const float* __restrict__ wv, const float* __restrict__ bv,
    const float* __restrict__ w_ih, const float* __restrict__ b_ih,
    const float* __restrict__ w_hh, const float* __restrict__ b_hh,
    const float* __restrict__ w1, const float* __restrict__ b1,
    const float* __restrict__ w2, const float* __restrict__ b2,
    const float* __restrict__ g_ff, const float* __restrict__ beta_ff,
    const float* __restrict__ M, const float* __restrict__ cvec,
    const float* __restrict__ uvec, const float* __restrict__ s0v,
    const float* __restrict__ g_sl, const float* __restrict__ beta_sl,
    float* __restrict__ qk, float* __restrict__ qb, int do_next)
{
  slot_update_wave(blockIdx.x, threadIdx.x, do_next,
                   S_in, S_out, acc, asum, wv, bv, w_ih, b_ih, w_hh, b_hh,
                   w1, b1, w2, b2, g_ff, beta_ff, M, cvec, uvec, s0v,
                   g_sl, beta_sl, qk, qb);
}

// ---------------------------------------------------------------------------
// Main streaming pass. grid = (CHUNKS, 64), block = 256.
__global__ __launch_bounds__(256) void k_main(
    const float* __restrict__ inputs,
    const float* __restrict__ g_in, const float* __restrict__ beta_in,
    const float* __restrict__ qk, const float* __restrict__ qb,
    float* __restrict__ acc, float* __restrict__ asum)
{
  __shared__ float lds_acc[4][512];
  __shared__ float lds_as[4][8];
  const int b = blockIdx.y;
  const int chunk = blockIdx.x;
  const int tid = threadIdx.x;
  const int lane = tid & 63;
  const int wave = tid >> 6;
  const int p = lane & 15;

  float4 g4  = ((const float4*)g_in)[p];
  float4 be4 = ((const float4*)beta_in)[p];
  float4 qkv[8];
  float qbv[8];
  const float4* qk4 = (const float4*)(qk + b * 512);
#pragma unroll
  for (int i = 0; i < 8; ++i) {
    qkv[i] = qk4[i * 16 + p];
    qbv[i] = qb[b * 8 + i];
  }

  float4 accl[8];
  float asl[8];
#pragma unroll
  for (int i = 0; i < 8; ++i) { accl[i] = make_float4(0.f, 0.f, 0.f, 0.f); asl[i] = 0.f; }

  const float4* in4 = (const float4*)(inputs + (size_t)b * 4096 * 64);
  const int rb0 = chunk * 128 + wave * 4;

  float4 xv = in4[rb0 * 16 + lane];
  for (int it = 0; it < 8; ++it) {
    float4 nxt;
    if (it < 7) nxt = in4[(rb0 + (it + 1) * 16) * 16 + lane];  // prefetch

    float s  = red16(xv.x + xv.y + xv.z + xv.w);
    float s2 = red16(xv.x * xv.x + xv.y * xv.y + xv.z * xv.z + xv.w * xv.w);
    float mean = s * 0.015625f;
    float var  = s2 * 0.015625f - mean * mean;
    float rstd = rsqrtf(var + LN_EPS);
    float4 xln;
    xln.x = (xv.x - mean) * rstd * g4.x + be4.x;
    xln.y = (xv.y - mean) * rstd * g4.y + be4.y;
    xln.z = (xv.z - mean) * rstd * g4.z + be4.z;
    xln.w = (xv.w - mean) * rstd * g4.w + be4.w;

    float dots[8];
#pragma unroll
    for (int i = 0; i < 8; ++i) {
      float d = xln.x * qkv[i].x + xln.y * qkv[i].y + xln.z * qkv[i].z + xln.w * qkv[i].w;
      dots[i] = red16(d) + qbv[i];
    }

    float mx = dots[0];
#pragma unroll
    for (int i = 1; i < 8; ++i) mx = fmaxf(mx, dots[i]);
    float pv[8];
    float ps = 0.0f;
#pragma unroll
    for (int i = 0; i < 8; ++i) { pv[i] = __expf(dots[i] - mx); ps += pv[i]; }
    float inv = __builtin_amdgcn_rcpf(ps);
#pragma unroll
    for (int i = 0; i < 8; ++i) {
      float pp = pv[i] * inv + EPS_ATTN;
      asl[i] += pp;
      accl[i].x += pp * xln.x;
      accl[i].y += pp * xln.y;
      accl[i].z += pp * xln.z;
      accl[i].w += pp * xln.w;
    }
    xv = nxt;
  }

#pragma unroll
  for (int i = 0; i < 8; ++i) {
#pragma unroll
    for (int m = 16; m <= 32; m <<= 1) {
      accl[i].x += __shfl_xor(accl[i].x, m, 64);
      accl[i].y += __shfl_xor(accl[i].y, m, 64);
      accl[i].z += __shfl_xor(accl[i].z, m, 64);
      accl[i].w += __shfl_xor(accl[i].w, m, 64);
      asl[i]    += __shfl_xor(asl[i], m, 64);
    }
  }

  if (lane < 16) {
    float4* dst = (float4*)lds_acc[wave];
#pragma unroll
    for (int i = 0; i < 8; ++i) dst[i * 16 + p] = accl[i];
  }
  if (lane == 0) {
#pragma unroll
    for (int i = 0; i < 8; ++i) lds_as[wave][i] = asl[i];
  }
  __syncthreads();

  for (int f = tid; f < 512; f += 256) {
    float ssum = lds_acc[0][f] + lds_acc[1][f] + lds_acc[2][f] + lds_acc[3][f];
    atomicAdd(&acc[b * 512 + f], ssum);
  }
  if (tid < 8) {
    float ssum = lds_as[0][tid] + lds_as[1][tid] + lds_as[2][tid] + lds_as[3][tid];
    atomicAdd(&asum[b * 8 + tid], ssum);
  }
}

// ---------------------------------------------------------------------------
extern "C" void kernel_launch(void* const* d_in, const int* in_sizes, int n_in,
                              void* d_out, int out_size, void* d_ws, size_t ws_size,
                              hipStream_t stream) {
  const float* inputs  = (const float*)d_in[0];
  const float* noise   = (const float*)d_in[1];
  const float* mu      = (const float*)d_in[2];
  const float* lsig    = (const float*)d_in[3];
  const float* wq      = (const float*)d_in[4];
  const float* bq      = (const float*)d_in[5];
  const float* wk      = (const float*)d_in[6];
  const float* bk      = (const float*)d_in[7];
  const float* wv      = (const float*)d_in[8];
  const float* bv      = (const float*)d_in[9];
  const float* w_ih    = (const float*)d_in[10];
  const float* b_ih    = (const float*)d_in[11];
  const float* w_hh    = (const float*)d_in[12];
  const float* b_hh    = (const float*)d_in[13];
  const float* w1      = (const float*)d_in[14];
  const float* b1      = (const float*)d_in[15];
  const float* w2      = (const float*)d_in[16];
  const float* b2      = (const float*)d_in[17];
  const float* g_in    = (const float*)d_in[18];
  const float* beta_in = (const float*)d_in[19];
  const float* g_sl    = (const float*)d_in[20];
  const float* beta_sl = (const float*)d_in[21];
  const float* g_ff    = (const float*)d_in[22];
  const float* beta_ff = (const float*)d_in[23];

  float* S_buf = (float*)d_ws;        // [64*8*64]
  float* qk    = S_buf + 32768;       // [64*8*64]
  float* qb    = qk + 32768;          // [64*8]
  float* acc   = qb + 512;            // [64*8*64]
  float* asum  = acc + 32768;         // [64*8]
  float* M     = asum + 512;          // [64*64]
  float* cvec  = M + 4096;            // [64]
  float* uvec  = cvec + 64;           // [64]
  float* s0v   = uvec + 64;           // [1]
  float* out   = (float*)d_out;

  k_prep<<<16, 256, 0, stream>>>(wq, wk, bq, bk, M, cvec, uvec, s0v);
  k_init<<<512, 64, 0, stream>>>(noise, mu, lsig, M, cvec, uvec, s0v,
                                 g_sl, beta_sl, S_buf, qk, qb, acc, asum);

  for (int t = 0; t < 3; ++t) {
    k_main<<<dim3(CHUNKS, 64), 256, 0, stream>>>(inputs, g_in, beta_in,
                                                 qk, qb, acc, asum);
    float* dst = (t == 2) ? out : S_buf;
    k_update<<<512, 64, 0, stream>>>(S_buf, dst, acc, asum, wv, bv,
                                     w_ih, b_ih, w_hh, b_hh, w1, b1, w2, b2,
                                     g_ff, beta_ff, M, cvec, uvec, s0v,
                                     g_sl, beta_sl, qk, qb, (t == 2) ? 0 : 1);
  }
}

// Round 10
// 229.521 us; speedup vs baseline: 7.0644x; 1.0586x over previous
//
#include <hip/hip_runtime.h>
#include <math.h>

#define LN_EPS 1e-5f
#define EPS_ATTN 1e-8f
#define SCALE 0.125f  // D^-0.5, D=64
#define CHUNKS 16

// ---------------------------------------------------------------------------
__device__ __forceinline__ float wsum64(float v) {
#pragma unroll
  for (int m = 1; m <= 32; m <<= 1) v += __shfl_xor(v, m, 64);
  return v;
}

// 16-lane allreduce sum on the VALU pipe via DPP (no LDS-pipe traffic).
__device__ __forceinline__ float red16(float v) {
  v += __int_as_float(__builtin_amdgcn_update_dpp(0, __float_as_int(v), 0xB1, 0xF, 0xF, true));
  v += __int_as_float(__builtin_amdgcn_update_dpp(0, __float_as_int(v), 0x4E, 0xF, 0xF, true));
  v += __int_as_float(__builtin_amdgcn_update_dpp(0, __float_as_int(v), 0x124, 0xF, 0xF, true));
  v += __int_as_float(__builtin_amdgcn_update_dpp(0, __float_as_int(v), 0x128, 0xF, 0xF, true));
  return v;
}

// ---------------------------------------------------------------------------
// Wave-local slot->qk: one wave, lane=d (uses precomputed M/cvec/uvec/s0).
__device__ void slot_qk_wave(int bi, float o, int lane,
    const float* __restrict__ M, const float* __restrict__ cvec,
    const float* __restrict__ uvec, const float* __restrict__ s0v,
    const float* __restrict__ g_sl, const float* __restrict__ beta_sl,
    float* __restrict__ qk, float* __restrict__ qb)
{
  float s  = wsum64(o);
  float s2 = wsum64(o * o);
  float mean = s * (1.0f / 64.0f);
  float var  = s2 * (1.0f / 64.0f) - mean * mean;
  float rstd = rsqrtf(var + LN_EPS);
  float ln = (o - mean) * rstd * g_sl[lane] + beta_sl[lane];

  float qv = cvec[lane];
#pragma unroll
  for (int t = 0; t < 64; ++t) qv += __shfl(ln, t, 64) * M[t * 64 + lane];
  qk[bi * 64 + lane] = qv;
  float pb = wsum64(ln * uvec[lane]);
  if (lane == 0) qb[bi] = s0v[0] + pb;
}

// ---------------------------------------------------------------------------
// Wave-local full slot update: one wave, lane=d. Zero barriers on the chain.
__device__ void slot_update_wave(int bi, int lane, int do_next,
    const float* __restrict__ S_in, float* __restrict__ S_out,
    float* __restrict__ acc, float* __restrict__ asum,
    const float* __restrict__ wv, const float* __restrict__ bv,
    const float* __restrict__ w_ih, const float* __restrict__ b_ih,
    const float* __restrict__ w_hh, const float* __restrict__ b_hh,
    const float* __restrict__ w1, const float* __restrict__ b1,
    const float* __restrict__ w2, const float* __restrict__ b2,
    const float* __restrict__ g_ff, const float* __restrict__ beta_ff,
    const float* __restrict__ M, const float* __restrict__ cvec,
    const float* __restrict__ uvec, const float* __restrict__ s0v,
    const float* __restrict__ g_sl, const float* __restrict__ beta_sl,
    float* __restrict__ qk, float* __restrict__ qb)
{
  float asv = asum[bi];
  float av  = acc[bi * 64 + lane];
  float v   = av / asv;
  if (do_next) {
    acc[bi * 64 + lane] = 0.0f;
    if (lane == 0) asum[bi] = 0.0f;
  }
  float sp = S_in[bi * 64 + lane];

  float upd = bv[lane];
#pragma unroll
  for (int e = 0; e < 64; ++e) upd += __shfl(v, e, 64) * wv[e * 64 + lane];

  float gxr = b_ih[lane], gxz = b_ih[64 + lane], gxn = b_ih[128 + lane];
  float ghr = b_hh[lane], ghz = b_hh[64 + lane], ghn = b_hh[128 + lane];
#pragma unroll 16
  for (int e = 0; e < 64; ++e) {
    float uu = __shfl(upd, e, 64), hh = __shfl(sp, e, 64);
    const float* wi = w_ih + e * 192;
    const float* wh = w_hh + e * 192;
    gxr += uu * wi[lane]; gxz += uu * wi[64 + lane]; gxn += uu * wi[128 + lane];
    ghr += hh * wh[lane]; ghz += hh * wh[64 + lane]; ghn += hh * wh[128 + lane];
  }
  float r  = 1.0f / (1.0f + __expf(-(gxr + ghr)));
  float z  = 1.0f / (1.0f + __expf(-(gxz + ghz)));
  float nw = tanhf(gxn + r * ghn);
  float sn = (1.0f - z) * nw + z * sp;

  float s  = wsum64(sn);
  float s2 = wsum64(sn * sn);
  float mean = s * (1.0f / 64.0f);
  float var  = s2 * (1.0f / 64.0f) - mean * mean;
  float rstd = rsqrtf(var + LN_EPS);
  float ff = (sn - mean) * rstd * g_ff[lane] + beta_ff[lane];

  float h1 = b1[lane], h2 = b1[64 + lane];
#pragma unroll
  for (int e = 0; e < 64; ++e) {
    float f = __shfl(ff, e, 64);
    h1 += f * w1[e * 128 + lane];
    h2 += f * w1[e * 128 + 64 + lane];
  }
  h1 = fmaxf(h1, 0.0f);
  h2 = fmaxf(h2, 0.0f);

  float o = sn + b2[lane];
#pragma unroll
  for (int t = 0; t < 64; ++t) o += __shfl(h1, t, 64) * w2[t * 64 + lane];
#pragma unroll
  for (int t = 0; t < 64; ++t) o += __shfl(h2, t, 64) * w2[(64 + t) * 64 + lane];

  S_out[bi * 64 + lane] = o;

  if (do_next)
    slot_qk_wave(bi, o, lane, M, cvec, uvec, s0v, g_sl, beta_sl, qk, qb);
}

// ---------------------------------------------------------------------------
// Init + prep fused (7 nodes total). grid = 577 blocks x 64 lanes.
//  blocks 0..511  : slot init; qk computed DIRECTLY (no M dependency —
//                   M is being built concurrently by blocks 512+).
//  blocks 512..575: M row t = bi-512, plus uvec[t].
//  block  576     : cvec + s0.
__global__ __launch_bounds__(64) void k_init(
    const float* __restrict__ noise, const float* __restrict__ mu,
    const float* __restrict__ lsig,
    const float* __restrict__ wq, const float* __restrict__ bq,
    const float* __restrict__ wk, const float* __restrict__ bk,
    const float* __restrict__ g_sl, const float* __restrict__ beta_sl,
    float* __restrict__ S_buf, float* __restrict__ qk, float* __restrict__ qb,
    float* __restrict__ acc, float* __restrict__ asum,
    float* __restrict__ M, float* __restrict__ cvec,
    float* __restrict__ uvec, float* __restrict__ s0v)
{
  int bi = blockIdx.x;
  int lane = threadIdx.x;
  if (bi < 512) {
    float sl = mu[lane] + __expf(lsig[lane]) * noise[bi * 64 + lane];
    S_buf[bi * 64 + lane] = sl;
    acc[bi * 64 + lane] = 0.0f;
    if (lane == 0) asum[bi] = 0.0f;

    float s  = wsum64(sl);
    float s2 = wsum64(sl * sl);
    float mean = s * (1.0f / 64.0f);
    float var  = s2 * (1.0f / 64.0f) - mean * mean;
    float rstd = rsqrtf(var + LN_EPS);
    float ln = (sl - mean) * rstd * g_sl[lane] + beta_sl[lane];

    float q = bq[lane];
#pragma unroll
    for (int t = 0; t < 64; ++t) q += __shfl(ln, t, 64) * wq[t * 64 + lane];
    float qkl = 0.0f;
#pragma unroll
    for (int d = 0; d < 64; ++d) qkl += __shfl(q, d, 64) * wk[lane * 64 + d];
    qk[bi * 64 + lane] = qkl * SCALE;
    float qbl = wsum64(q * bk[lane]);
    if (lane == 0) qb[bi] = qbl * SCALE;
  } else if (bi < 576) {
    int t = bi - 512;
    float wqv = wq[t * 64 + lane];
    float m = 0.0f;
#pragma unroll
    for (int d = 0; d < 64; ++d) m += __shfl(wqv, d, 64) * wk[lane * 64 + d];
    M[t * 64 + lane] = m * SCALE;
    float uv = wsum64(wqv * bk[lane]);
    if (lane == 0) uvec[t] = uv * SCALE;
  } else {
    float bqv = bq[lane];
    float cc = 0.0f;
#pragma unroll
    for (int j = 0; j < 64; ++j) cc += __shfl(bqv, j, 64) * wk[lane * 64 + j];
    cvec[lane] = cc * SCALE;
    float ss = wsum64(bq[lane] * bk[lane]);
    if (lane == 0) s0v[0] = ss * SCALE;
  }
}

// ---------------------------------------------------------------------------
// Per-slot update: 512 blocks x 64 lanes, fully parallel wave-local chains.
__global__ __launch_bounds__(64) void k_update(
    const float* __restrict__ S_in, float* __restrict__ S_out,
    float* __restrict__ acc, float* __restrict__ asum,
    const float* __restrict__ wv, const float* __restrict__ bv,
    const float* __restrict__ w_ih, const float* __restrict__ b_ih,
    const float* __restrict__ w_hh, const float* __restrict__ b_hh,
    const float* __restrict__ w1, const float* __restrict__ b1,
    const float* __restrict__ w2, const float* __restrict__ b2,
    const float* __restrict__ g_ff, const float* __restrict__ beta_ff,
    const float* __restrict__ M, const float* __restrict__ cvec,
    const float* __restrict__ uvec, const float* __restrict__ s0v,
    const float* __restrict__ g_sl, const float* __restrict__ beta_sl,
    float* __restrict__ qk, float* __restrict__ qb, int do_next)
{
  slot_update_wave(blockIdx.x, threadIdx.x, do_next,
                   S_in, S_out, acc, asum, wv, bv, w_ih, b_ih, w_hh, b_hh,
                   w1, b1, w2, b2, g_ff, beta_ff, M, cvec, uvec, s0v,
                   g_sl, beta_sl, qk, qb);
}

// ---------------------------------------------------------------------------
// Main streaming pass. grid = (CHUNKS, 64), block = 256.
// 8 rows per wave-iter: two independent 4-row groups (A/B) double the
// number of independent DPP/exp chains in flight per wave.
__global__ __launch_bounds__(256) void k_main(
    const float* __restrict__ inputs,
    const float* __restrict__ g_in, const float* __restrict__ beta_in,
    const float* __restrict__ qk, const float* __restrict__ qb,
    float* __restrict__ acc, float* __restrict__ asum)
{
  __shared__ float lds_acc[4][512];
  __shared__ float lds_as[4][8];
  const int b = blockIdx.y;
  const int chunk = blockIdx.x;
  const int tid = threadIdx.x;
  const int lane = tid & 63;
  const int wave = tid >> 6;
  const int p = lane & 15;

  float4 g4  = ((const float4*)g_in)[p];
  float4 be4 = ((const float4*)beta_in)[p];
  float4 qkv[8];
  float qbv[8];
  const float4* qk4 = (const float4*)(qk + b * 512);
#pragma unroll
  for (int i = 0; i < 8; ++i) {
    qkv[i] = qk4[i * 16 + p];
    qbv[i] = qb[b * 8 + i];
  }

  float4 accl[8];
  float asl[8];
#pragma unroll
  for (int i = 0; i < 8; ++i) { accl[i] = make_float4(0.f, 0.f, 0.f, 0.f); asl[i] = 0.f; }

  const float4* in4 = (const float4*)(inputs + (size_t)b * 4096 * 64);
  const int rb0 = chunk * 256 + wave * 8;  // this wave's iter-0 base row

  float4 xa = in4[rb0 * 16 + lane];
  float4 xb = in4[(rb0 + 4) * 16 + lane];
  for (int it = 0; it < 8; ++it) {
    float4 na, nb;
    if (it < 7) {
      na = in4[(rb0 + (it + 1) * 32) * 16 + lane];
      nb = in4[(rb0 + (it + 1) * 32 + 4) * 16 + lane];
    }

    // ---- group A ----
    {
      float s  = red16(xa.x + xa.y + xa.z + xa.w);
      float s2 = red16(xa.x * xa.x + xa.y * xa.y + xa.z * xa.z + xa.w * xa.w);
      float mean = s * 0.015625f;
      float var  = s2 * 0.015625f - mean * mean;
      float rstd = rsqrtf(var + LN_EPS);
      float4 xln;
      xln.x = (xa.x - mean) * rstd * g4.x + be4.x;
      xln.y = (xa.y - mean) * rstd * g4.y + be4.y;
      xln.z = (xa.z - mean) * rstd * g4.z + be4.z;
      xln.w = (xa.w - mean) * rstd * g4.w + be4.w;
      float dots[8];
#pragma unroll
      for (int i = 0; i < 8; ++i) {
        float d = xln.x * qkv[i].x + xln.y * qkv[i].y + xln.z * qkv[i].z + xln.w * qkv[i].w;
        dots[i] = red16(d) + qbv[i];
      }
      // softmax over slots, no max-subtraction (|dots| << 88)
      float pv[8];
      float ps = 0.0f;
#pragma unroll
      for (int i = 0; i < 8; ++i) { pv[i] = __expf(dots[i]); ps += pv[i]; }
      float inv = __builtin_amdgcn_rcpf(ps);
#pragma unroll
      for (int i = 0; i < 8; ++i) {
        float pp = pv[i] * inv + EPS_ATTN;
        asl[i] += pp;
        accl[i].x += pp * xln.x;
        accl[i].y += pp * xln.y;
        accl[i].z += pp * xln.z;
        accl[i].w += pp * xln.w;
      }
    }
    // ---- group B ----
    {
      float s  = red16(xb.x + xb.y + xb.z + xb.w);
      float s2 = red16(xb.x * xb.x + xb.y * xb.y + xb.z * xb.z + xb.w * xb.w);
      float mean = s * 0.015625f;
      float var  = s2 * 0.015625f - mean * mean;
      float rstd = rsqrtf(var + LN_EPS);
      float4 xln;
      xln.x = (xb.x - mean) * rstd * g4.x + be4.x;
      xln.y = (xb.y - mean) * rstd * g4.y + be4.y;
      xln.z = (xb.z - mean) * rstd * g4.z + be4.z;
      xln.w = (xb.w - mean) * rstd * g4.w + be4.w;
      float dots[8];
#pragma unroll
      for (int i = 0; i < 8; ++i) {
        float d = xln.x * qkv[i].x + xln.y * qkv[i].y + xln.z * qkv[i].z + xln.w * qkv[i].w;
        dots[i] = red16(d) + qbv[i];
      }
      float pv[8];
      float ps = 0.0f;
#pragma unroll
      for (int i = 0; i < 8; ++i) { pv[i] = __expf(dots[i]); ps += pv[i]; }
      float inv = __builtin_amdgcn_rcpf(ps);
#pragma unroll
      for (int i = 0; i < 8; ++i) {
        float pp = pv[i] * inv + EPS_ATTN;
        asl[i] += pp;
        accl[i].x += pp * xln.x;
        accl[i].y += pp * xln.y;
        accl[i].z += pp * xln.z;
        accl[i].w += pp * xln.w;
      }
    }
    xa = na;
    xb = nb;
  }

#pragma unroll
  for (int i = 0; i < 8; ++i) {
#pragma unroll
    for (int m = 16; m <= 32; m <<= 1) {
      accl[i].x += __shfl_xor(accl[i].x, m, 64);
      accl[i].y += __shfl_xor(accl[i].y, m, 64);
      accl[i].z += __shfl_xor(accl[i].z, m, 64);
      accl[i].w += __shfl_xor(accl[i].w, m, 64);
      asl[i]    += __shfl_xor(asl[i], m, 64);
    }
  }

  if (lane < 16) {
    float4* dst = (float4*)lds_acc[wave];
#pragma unroll
    for (int i = 0; i < 8; ++i) dst[i * 16 + p] = accl[i];
  }
  if (lane == 0) {
#pragma unroll
    for (int i = 0; i < 8; ++i) lds_as[wave][i] = asl[i];
  }
  __syncthreads();

  for (int f = tid; f < 512; f += 256) {
    float ssum = lds_acc[0][f] + lds_acc[1][f] + lds_acc[2][f] + lds_acc[3][f];
    atomicAdd(&acc[b * 512 + f], ssum);
  }
  if (tid < 8) {
    float ssum = lds_as[0][tid] + lds_as[1][tid] + lds_as[2][tid] + lds_as[3][tid];
    atomicAdd(&asum[b * 8 + tid], ssum);
  }
}

// ---------------------------------------------------------------------------
extern "C" void kernel_launch(void* const* d_in, const int* in_sizes, int n_in,
                              void* d_out, int out_size, void* d_ws, size_t ws_size,
                              hipStream_t stream) {
  const float* inputs  = (const float*)d_in[0];
  const float* noise   = (const float*)d_in[1];
  const float* mu      = (const float*)d_in[2];
  const float* lsig    = (const float*)d_in[3];
  const float* wq      = (const float*)d_in[4];
  const float* bq      = (const float*)d_in[5];
  const float* wk      = (const float*)d_in[6];
  const float* bk      = (const float*)d_in[7];
  const float* wv      = (const float*)d_in[8];
  const float* bv      = (const float*)d_in[9];
  const float* w_ih    = (const float*)d_in[10];
  const float* b_ih    = (const float*)d_in[11];
  const float* w_hh    = (const float*)d_in[12];
  const float* b_hh    = (const float*)d_in[13];
  const float* w1      = (const float*)d_in[14];
  const float* b1      = (const float*)d_in[15];
  const float* w2      = (const float*)d_in[16];
  const float* b2      = (const float*)d_in[17];
  const float* g_in    = (const float*)d_in[18];
  const float* beta_in = (const float*)d_in[19];
  const float* g_sl    = (const float*)d_in[20];
  const float* beta_sl = (const float*)d_in[21];
  const float* g_ff    = (const float*)d_in[22];
  const float* beta_ff = (const float*)d_in[23];

  float* S_buf = (float*)d_ws;        // [64*8*64]
  float* qk    = S_buf + 32768;       // [64*8*64]
  float* qb    = qk + 32768;          // [64*8]
  float* acc   = qb + 512;            // [64*8*64]
  float* asum  = acc + 32768;         // [64*8]
  float* M     = asum + 512;          // [64*64]
  float* cvec  = M + 4096;            // [64]
  float* uvec  = cvec + 64;           // [64]
  float* s0v   = uvec + 64;           // [1]
  float* out   = (float*)d_out;

  k_init<<<577, 64, 0, stream>>>(noise, mu, lsig, wq, bq, wk, bk,
                                 g_sl, beta_sl, S_buf, qk, qb, acc, asum,
                                 M, cvec, uvec, s0v);

  for (int t = 0; t < 3; ++t) {
    k_main<<<dim3(CHUNKS, 64), 256, 0, stream>>>(inputs, g_in, beta_in,
                                                 qk, qb, acc, asum);
    float* dst = (t == 2) ? out : S_buf;
    k_update<<<512, 64, 0, stream>>>(S_buf, dst, acc, asum, wv, bv,
                                     w_ih, b_ih, w_hh, b_hh, w1, b1, w2, b2,
                                     g_ff, beta_ff, M, cvec, uvec, s0v,
                                     g_sl, beta_sl, qk, qb, (t == 2) ? 0 : 1);
  }
}